// Round 1
// baseline (21331.970 us; speedup 1.0000x reference)
//
#include <hip/hip_runtime.h>
#include <hip/hip_bf16.h>

#define D 64
#define R 128
#define NSTEPS 8

#define SELU_SCALE 1.0507009873554805f
#define SELU_ALPHA 1.6732632423543772f

__device__ __forceinline__ float sigmoid_f(float x) {
    return 1.0f / (1.0f + __expf(-x));
}

// ---------------------------------------------------------------------------
// Message kernel: thread-per-message.
// msg = selu([h[first], h[second]] @ W_msg + b_msg); agg[second] += msg
// Weights read with wave-uniform indices -> scalar loads (SGPR-resident rows).
// ---------------------------------------------------------------------------
__device__ __forceinline__ void msg_fma(float* acc, float xv, const float* __restrict__ wrow) {
    #pragma unroll
    for (int j = 0; j < D; ++j) acc[j] = fmaf(xv, wrow[j], acc[j]);
}

__global__ __launch_bounds__(256) void msg_kernel(
    const float* __restrict__ h,
    const int* __restrict__ first,
    const int* __restrict__ second,
    const float* __restrict__ Wm,   // [2D][D]
    const float* __restrict__ bm,   // [D]
    float* __restrict__ agg,        // [E][D]
    int M)
{
    int m = blockIdx.x * blockDim.x + threadIdx.x;
    if (m >= M) return;
    int f = first[m];
    int s = second[m];
    const float4* hf4 = reinterpret_cast<const float4*>(h + (size_t)f * D);
    const float4* hs4 = reinterpret_cast<const float4*>(h + (size_t)s * D);

    float acc[D];
    #pragma unroll
    for (int j = 0; j < D; ++j) acc[j] = bm[j];

    #pragma unroll 1
    for (int kk = 0; kk < D / 4; ++kk) {
        float4 a = hf4[kk];
        const float* w = Wm + (size_t)(kk * 4) * D;
        msg_fma(acc, a.x, w);
        msg_fma(acc, a.y, w + D);
        msg_fma(acc, a.z, w + 2 * D);
        msg_fma(acc, a.w, w + 3 * D);
    }
    #pragma unroll 1
    for (int kk = 0; kk < D / 4; ++kk) {
        float4 a = hs4[kk];
        const float* w = Wm + (size_t)(D + kk * 4) * D;
        msg_fma(acc, a.x, w);
        msg_fma(acc, a.y, w + D);
        msg_fma(acc, a.z, w + 2 * D);
        msg_fma(acc, a.w, w + 3 * D);
    }

    float* ar = agg + (size_t)s * D;
    #pragma unroll
    for (int j = 0; j < D; ++j) {
        float v = acc[j];
        v = (v > 0.0f) ? (SELU_SCALE * v)
                       : (SELU_SCALE * SELU_ALPHA) * (__expf(v) - 1.0f);
        unsafeAtomicAdd(ar + j, v);
    }
}

// ---------------------------------------------------------------------------
// Update GRU kernel (units=64): wave-per-edge x UPD_EPW edges, lane = column.
// h = GRU(agg, h). Also re-zeros agg for the next step after consuming it.
// ---------------------------------------------------------------------------
#define UPD_BLOCK 512
#define UPD_WAVES 8
#define UPD_EPW 4

__global__ __launch_bounds__(UPD_BLOCK, 1) void upd_kernel(
    float* __restrict__ agg,        // [E][D], consumed then zeroed
    float* __restrict__ h,          // [E][D] in/out
    const float* __restrict__ Wu,   // [D][3D]
    const float* __restrict__ Uu,   // [D][3D]
    const float* __restrict__ bu,   // [2][3D]
    int E)
{
    __shared__ float Wl[D * 3 * D];   // 48KB
    __shared__ float Ul[D * 3 * D];   // 48KB
    __shared__ float xs[UPD_WAVES][UPD_EPW][D];
    __shared__ float hs[UPD_WAVES][UPD_EPW][D];

    for (int i = threadIdx.x; i < D * 3 * D; i += UPD_BLOCK) {
        Wl[i] = Wu[i];
        Ul[i] = Uu[i];
    }
    __syncthreads();

    const int lane = threadIdx.x & 63;
    const int w = threadIdx.x >> 6;
    const int e0 = (blockIdx.x * UPD_WAVES + w) * UPD_EPW;

    #pragma unroll
    for (int ee = 0; ee < UPD_EPW; ++ee) {
        int e = e0 + ee;
        bool v = (e < E);
        float xv = v ? agg[(size_t)e * D + lane] : 0.0f;
        float hv = v ? h[(size_t)e * D + lane] : 0.0f;
        xs[w][ee][lane] = xv;
        hs[w][ee][lane] = hv;
        if (v) agg[(size_t)e * D + lane] = 0.0f;   // pre-zero for next step
    }

    // biases: z cols [0,64), r [64,128), cand [128,192); bu[1] at offset 192
    float bz  = bu[lane]       + bu[192 + lane];
    float brr = bu[64 + lane]  + bu[192 + 64 + lane];
    float bcx = bu[128 + lane];
    float bch = bu[192 + 128 + lane];

    float az[UPD_EPW], ar_[UPD_EPW], acx[UPD_EPW], ach[UPD_EPW];
    #pragma unroll
    for (int ee = 0; ee < UPD_EPW; ++ee) {
        az[ee] = bz; ar_[ee] = brr; acx[ee] = bcx; ach[ee] = bch;
    }

    #pragma unroll 2
    for (int k = 0; k < D; ++k) {
        float wz = Wl[k * 192 + lane];
        float wr = Wl[k * 192 + 64 + lane];
        float wc = Wl[k * 192 + 128 + lane];
        float uz = Ul[k * 192 + lane];
        float ur = Ul[k * 192 + 64 + lane];
        float uc = Ul[k * 192 + 128 + lane];
        #pragma unroll
        for (int ee = 0; ee < UPD_EPW; ++ee) {
            float xk = xs[w][ee][k];
            float hk = hs[w][ee][k];
            az[ee]  = fmaf(xk, wz, az[ee]);
            az[ee]  = fmaf(hk, uz, az[ee]);
            ar_[ee] = fmaf(xk, wr, ar_[ee]);
            ar_[ee] = fmaf(hk, ur, ar_[ee]);
            acx[ee] = fmaf(xk, wc, acx[ee]);
            ach[ee] = fmaf(hk, uc, ach[ee]);
        }
    }

    #pragma unroll
    for (int ee = 0; ee < UPD_EPW; ++ee) {
        int e = e0 + ee;
        if (e >= E) continue;
        float z = sigmoid_f(az[ee]);
        float r = sigmoid_f(ar_[ee]);
        float c = tanhf(fmaf(r, ach[ee], acx[ee]));
        float hp = hs[w][ee][lane];
        float hn = z * hp + (1.0f - z) * c;
        h[(size_t)e * D + lane] = hn;
    }
}

// ---------------------------------------------------------------------------
// Readout GRU kernel (units=128): split by output base-column half (ch=0/1).
// Each half's GRU coupling (cols c, 128+c, 256+c) is self-contained.
// Weight slices staged in LDS (48KB + 96KB). Broadcasts via __shfl.
// hro double-buffered (both halves read hro_in, write disjoint hro_out cols).
// ---------------------------------------------------------------------------
#define RO_BLOCK 512
#define RO_WAVES 8
#define RO_EPW 2

__global__ __launch_bounds__(RO_BLOCK, 1) void ro_kernel(
    const float* __restrict__ x_in,     // [E][D]   (current mp state)
    const float* __restrict__ hro_in,   // [E][R]
    float* __restrict__ hro_out,        // [E][R]
    const float* __restrict__ Wr,       // [D][3R]
    const float* __restrict__ Ur,       // [R][3R]
    const float* __restrict__ br,       // [2][3R]
    int E, int ch)
{
    __shared__ float Wsl[D][3][64];     // 48KB : Wsl[k][g][j] = Wr[k][g*128 + ch*64 + j]
    __shared__ float Usl[R][3][64];     // 96KB

    for (int i = threadIdx.x; i < D * 3 * 64; i += RO_BLOCK) {
        int k = i / 192, g = (i % 192) >> 6, j = i & 63;
        Wsl[k][g][j] = Wr[(size_t)k * 384 + g * 128 + ch * 64 + j];
    }
    for (int i = threadIdx.x; i < R * 3 * 64; i += RO_BLOCK) {
        int k = i / 192, g = (i % 192) >> 6, j = i & 63;
        Usl[k][g][j] = Ur[(size_t)k * 384 + g * 128 + ch * 64 + j];
    }
    __syncthreads();

    const int lane = threadIdx.x & 63;
    const int w = threadIdx.x >> 6;
    const int c = ch * 64 + lane;      // base col in [0,128)
    const int e0 = (blockIdx.x * RO_WAVES + w) * RO_EPW;

    float xreg[RO_EPW], h0reg[RO_EPW], h1reg[RO_EPW];
    #pragma unroll
    for (int ee = 0; ee < RO_EPW; ++ee) {
        int e = e0 + ee;
        bool v = (e < E);
        xreg[ee]  = v ? x_in[(size_t)e * D + lane] : 0.0f;
        h0reg[ee] = v ? hro_in[(size_t)e * R + lane] : 0.0f;
        h1reg[ee] = v ? hro_in[(size_t)e * R + 64 + lane] : 0.0f;
    }

    float bz  = br[c]       + br[384 + c];
    float brr = br[128 + c] + br[384 + 128 + c];
    float bcx = br[256 + c];
    float bch = br[384 + 256 + c];

    float az[RO_EPW], ar_[RO_EPW], acx[RO_EPW], ach[RO_EPW];
    #pragma unroll
    for (int ee = 0; ee < RO_EPW; ++ee) {
        az[ee] = bz; ar_[ee] = brr; acx[ee] = bcx; ach[ee] = bch;
    }

    // x phase: k in [0,64)
    #pragma unroll 2
    for (int k = 0; k < D; ++k) {
        float wz = Wsl[k][0][lane];
        float wr = Wsl[k][1][lane];
        float wc = Wsl[k][2][lane];
        #pragma unroll
        for (int ee = 0; ee < RO_EPW; ++ee) {
            float xk = __shfl(xreg[ee], k);
            az[ee]  = fmaf(xk, wz, az[ee]);
            ar_[ee] = fmaf(xk, wr, ar_[ee]);
            acx[ee] = fmaf(xk, wc, acx[ee]);
        }
    }
    // h phase: k in [0,64) from h0reg
    #pragma unroll 2
    for (int k = 0; k < 64; ++k) {
        float uz = Usl[k][0][lane];
        float ur = Usl[k][1][lane];
        float uc = Usl[k][2][lane];
        #pragma unroll
        for (int ee = 0; ee < RO_EPW; ++ee) {
            float hk = __shfl(h0reg[ee], k);
            az[ee]  = fmaf(hk, uz, az[ee]);
            ar_[ee] = fmaf(hk, ur, ar_[ee]);
            ach[ee] = fmaf(hk, uc, ach[ee]);
        }
    }
    // h phase: k in [64,128) from h1reg
    #pragma unroll 2
    for (int k = 64; k < 128; ++k) {
        float uz = Usl[k][0][lane];
        float ur = Usl[k][1][lane];
        float uc = Usl[k][2][lane];
        #pragma unroll
        for (int ee = 0; ee < RO_EPW; ++ee) {
            float hk = __shfl(h1reg[ee], k - 64);
            az[ee]  = fmaf(hk, uz, az[ee]);
            ar_[ee] = fmaf(hk, ur, ar_[ee]);
            ach[ee] = fmaf(hk, uc, ach[ee]);
        }
    }

    #pragma unroll
    for (int ee = 0; ee < RO_EPW; ++ee) {
        int e = e0 + ee;
        if (e >= E) continue;
        float z = sigmoid_f(az[ee]);
        float r = sigmoid_f(ar_[ee]);
        float cand = tanhf(fmaf(r, ach[ee], acx[ee]));
        float hp = ch ? h1reg[ee] : h0reg[ee];   // hro_in[e][c]
        float hn = z * hp + (1.0f - z) * cand;
        hro_out[(size_t)e * R + c] = hn;
    }
}

// ---------------------------------------------------------------------------
// Output: out[g] = b_out + sum_{e: gid[e]==g} dot(hro[e], W_out)
// ---------------------------------------------------------------------------
__global__ void out_init_kernel(float* __restrict__ out, const float* __restrict__ b_out, int G) {
    int g = blockIdx.x * blockDim.x + threadIdx.x;
    if (g < G) out[g] = b_out[0];
}

__global__ __launch_bounds__(256) void out_kernel(
    const float* __restrict__ hro,
    const int* __restrict__ gid,
    const float* __restrict__ Wout,   // [R]
    float* __restrict__ out,
    int E)
{
    int e = blockIdx.x * blockDim.x + threadIdx.x;
    if (e >= E) return;
    const float4* hp = reinterpret_cast<const float4*>(hro + (size_t)e * R);
    float s = 0.0f;
    #pragma unroll
    for (int kk = 0; kk < R / 4; ++kk) {
        float4 a = hp[kk];
        s = fmaf(a.x, Wout[kk * 4 + 0], s);
        s = fmaf(a.y, Wout[kk * 4 + 1], s);
        s = fmaf(a.z, Wout[kk * 4 + 2], s);
        s = fmaf(a.w, Wout[kk * 4 + 3], s);
    }
    unsafeAtomicAdd(out + gid[e], s);
}

// ---------------------------------------------------------------------------
extern "C" void kernel_launch(void* const* d_in, const int* in_sizes, int n_in,
                              void* d_out, int out_size, void* d_ws, size_t ws_size,
                              hipStream_t stream) {
    const float* link_state = (const float*)d_in[0];
    const int*   first      = (const int*)d_in[1];
    const int*   second     = (const int*)d_in[2];
    const int*   gids       = (const int*)d_in[3];
    const float* Wm         = (const float*)d_in[5];
    const float* bm         = (const float*)d_in[6];
    const float* Wu         = (const float*)d_in[7];
    const float* Uu         = (const float*)d_in[8];
    const float* bu         = (const float*)d_in[9];
    const float* Wr         = (const float*)d_in[10];
    const float* Ur         = (const float*)d_in[11];
    const float* brb        = (const float*)d_in[12];
    const float* Wout       = (const float*)d_in[13];
    const float* bout       = (const float*)d_in[14];

    const int E = in_sizes[0] / D;
    const int M = in_sizes[1];
    const int G = out_size;

    float* h    = (float*)d_ws;                 // E*D
    float* agg  = h    + (size_t)E * D;         // E*D
    float* hro0 = agg  + (size_t)E * D;         // E*R
    float* hro1 = hro0 + (size_t)E * R;         // E*R

    hipMemcpyAsync(h, link_state, (size_t)E * D * sizeof(float),
                   hipMemcpyDeviceToDevice, stream);
    hipMemsetAsync(agg, 0, (size_t)E * D * sizeof(float), stream);
    hipMemsetAsync(hro0, 0, (size_t)E * R * sizeof(float), stream);

    float* ro_in = hro0;
    float* ro_out = hro1;

    const int msg_grid = (M + 255) / 256;
    const int upd_grid = (E + UPD_WAVES * UPD_EPW - 1) / (UPD_WAVES * UPD_EPW);
    const int ro_grid  = (E + RO_WAVES * RO_EPW - 1) / (RO_WAVES * RO_EPW);

    for (int t = 0; t < NSTEPS; ++t) {
        msg_kernel<<<msg_grid, 256, 0, stream>>>(h, first, second, Wm, bm, agg, M);
        upd_kernel<<<upd_grid, UPD_BLOCK, 0, stream>>>(agg, h, Wu, Uu, bu, E);
        ro_kernel<<<ro_grid, RO_BLOCK, 0, stream>>>(h, ro_in, ro_out, Wr, Ur, brb, E, 0);
        ro_kernel<<<ro_grid, RO_BLOCK, 0, stream>>>(h, ro_in, ro_out, Wr, Ur, brb, E, 1);
        float* tmp = ro_in; ro_in = ro_out; ro_out = tmp;
    }

    out_init_kernel<<<(G + 255) / 256, 256, 0, stream>>>((float*)d_out, bout, G);
    out_kernel<<<(E + 255) / 256, 256, 0, stream>>>(ro_in, gids, Wout, (float*)d_out, E);
}

// Round 2
// 1509.819 us; speedup vs baseline: 14.1288x; 14.1288x over previous
//
#include <hip/hip_runtime.h>
#include <hip/hip_bf16.h>

#define D 64
#define R 128
#define NSTEPS 8
#define SELU_SCALE 1.0507009873554805f
#define SELU_ALPHA 1.6732632423543772f

typedef _Float16 half8 __attribute__((ext_vector_type(8)));
typedef float f32x4 __attribute__((ext_vector_type(4)));

__device__ __forceinline__ float fast_sig(float x) {
    return __fdividef(1.0f, 1.0f + __expf(-x));
}
__device__ __forceinline__ float fast_tanh(float x) {
    float xc = fminf(fmaxf(x, -15.0f), 15.0f);
    float e = __expf(2.0f * xc);
    return 1.0f - __fdividef(2.0f, e + 1.0f);
}

// ---------------------------------------------------------------------------
// Prep: convert fp32 weight [K][N] into fp16 MFMA B-fragment order:
// dst[((nt*KT + kt)*64 + lane)*8 + j] = src[(32*kt + 8*(lane>>4) + j)*N + 16*nt + (lane&15)]
// ---------------------------------------------------------------------------
__global__ __launch_bounds__(256) void swizzle_w(const float* __restrict__ src,
                                                 _Float16* __restrict__ dst,
                                                 int K, int N) {
    int idx = blockIdx.x * 256 + threadIdx.x;
    int KT = K >> 5;
    int total = KT * (N >> 4) * 512;
    if (idx >= total) return;
    int j = idx & 7;
    int lane = (idx >> 3) & 63;
    int kt = (idx >> 9) % KT;
    int nt = idx / (512 * KT);
    int k = 32 * kt + 8 * (lane >> 4) + j;
    int n = 16 * nt + (lane & 15);
    dst[idx] = (_Float16)src[(size_t)k * N + n];
}

__global__ __launch_bounds__(256) void h16_init(const float* __restrict__ src,
                                                _Float16* __restrict__ dst, int n) {
    int i = blockIdx.x * 256 + threadIdx.x;
    if (i < n) dst[i] = (_Float16)src[i];
}

// ---------------------------------------------------------------------------
// CSR build: hist -> scan -> scatter (indices constant across steps)
// ---------------------------------------------------------------------------
__global__ __launch_bounds__(256) void hist_kernel(const int* __restrict__ second,
                                                   int* __restrict__ cnt, int M) {
    int m = blockIdx.x * 256 + threadIdx.x;
    if (m < M) atomicAdd(&cnt[second[m]], 1);
}

__global__ __launch_bounds__(1024) void scan_kernel(const int* __restrict__ cnt,
                                                    int* __restrict__ off, int E) {
    __shared__ int part[1024];
    int tid = threadIdx.x;
    int chunk = (E + 1023) >> 10;
    int base = tid * chunk;
    int s = 0;
    for (int i = 0; i < chunk; ++i) {
        int idx = base + i;
        if (idx < E) s += cnt[idx];
    }
    part[tid] = s;
    __syncthreads();
    for (int d = 1; d < 1024; d <<= 1) {
        int v = (tid >= d) ? part[tid - d] : 0;
        __syncthreads();
        part[tid] += v;
        __syncthreads();
    }
    int run = (tid == 0) ? 0 : part[tid - 1];
    for (int i = 0; i < chunk; ++i) {
        int idx = base + i;
        if (idx < E) { off[idx] = run; run += cnt[idx]; }
    }
}

__global__ __launch_bounds__(256) void scatter_kernel(const int* __restrict__ second,
                                                      const int* __restrict__ off,
                                                      int* __restrict__ cur,
                                                      int* __restrict__ perm, int M) {
    int m = blockIdx.x * 256 + threadIdx.x;
    if (m < M) {
        int s = second[m];
        int p = atomicAdd(&cur[s], 1);
        perm[off[s] + p] = m;
    }
}

// ---------------------------------------------------------------------------
// Message kernel (fp16 MFMA): wave = 16 messages in CSR (receiver-sorted)
// order. msg = selu([h[f],h[s]] @ Wm + bm); segmented run-sum -> contiguous
// 256B atomic bursts into agg (f32).
// ---------------------------------------------------------------------------
__global__ __launch_bounds__(256) void msg_mfma(
    const _Float16* __restrict__ h16,
    const int* __restrict__ first, const int* __restrict__ second,
    const int* __restrict__ perm,
    const half8* __restrict__ wB,   // [4nt][4kt][64] half8
    const float* __restrict__ bm,
    float* __restrict__ agg, int M)
{
    __shared__ float tile[4][16][64];
    __shared__ int skey[4][16];

    const int wid = threadIdx.x >> 6;
    const int lane = threadIdx.x & 63;
    const int t0 = (blockIdx.x * 4 + wid) * 16;

    // persistent B fragments (weights): 16 tiles x 4 VGPR
    half8 B[4][4];
    #pragma unroll
    for (int nt = 0; nt < 4; ++nt)
        #pragma unroll
        for (int kt = 0; kt < 4; ++kt)
            B[nt][kt] = wB[(nt * 4 + kt) * 64 + lane];

    int row = t0 + (lane & 15);
    bool rowv = (row < M);
    int pm = perm[min(row, M - 1)];
    int fi = first[pm];
    int si = second[pm];

    const half8* fr = reinterpret_cast<const half8*>(h16 + (size_t)fi * D);
    const half8* sr = reinterpret_cast<const half8*>(h16 + (size_t)si * D);
    const int hi = lane >> 4;
    half8 A[4];
    A[0] = fr[hi];
    A[1] = fr[4 + hi];
    A[2] = sr[hi];
    A[3] = sr[4 + hi];

    f32x4 acc[4];
    #pragma unroll
    for (int nt = 0; nt < 4; ++nt) acc[nt] = (f32x4){0.f, 0.f, 0.f, 0.f};

    #pragma unroll
    for (int nt = 0; nt < 4; ++nt)
        #pragma unroll
        for (int kt = 0; kt < 4; ++kt)
            acc[nt] = __builtin_amdgcn_mfma_f32_16x16x32_f16(A[kt], B[nt][kt], acc[nt], 0, 0, 0);

    // epilogue: bias + selu -> LDS
    #pragma unroll
    for (int nt = 0; nt < 4; ++nt) {
        int n = nt * 16 + (lane & 15);
        float bias = bm[n];
        #pragma unroll
        for (int r = 0; r < 4; ++r) {
            float v = acc[nt][r] + bias;
            v = (v > 0.0f) ? (SELU_SCALE * v)
                           : (SELU_SCALE * SELU_ALPHA) * (__expf(v) - 1.0f);
            tile[wid][(lane >> 4) * 4 + r][n] = v;
        }
    }
    if (lane < 16) skey[wid][lane] = rowv ? si : -1;
    __syncthreads();

    // segmented reduce over 16 rows; flush per run (contiguous 256B atomics)
    float run = 0.0f;
    int kprev = skey[wid][0];
    #pragma unroll
    for (int m = 0; m < 16; ++m) {
        int km = skey[wid][m];
        if (km != kprev) {
            if (kprev >= 0) unsafeAtomicAdd(agg + (size_t)kprev * D + lane, run);
            run = 0.0f;
            kprev = km;
        }
        run += tile[wid][m][lane];
    }
    if (kprev >= 0) unsafeAtomicAdd(agg + (size_t)kprev * D + lane, run);
}

// ---------------------------------------------------------------------------
// Update GRU (fp16 MFMA): wave = 16 edges. x = agg (f32, converted in-kernel,
// then zeroed for next step), h carried in f32 (h32) + f16 copy (h16).
// ---------------------------------------------------------------------------
__global__ __launch_bounds__(256) void upd_mfma(
    float* __restrict__ agg,
    float* __restrict__ h32,
    _Float16* __restrict__ h16,
    const half8* __restrict__ wWu,  // [12nt][2kt][64]
    const half8* __restrict__ wUu,  // [12nt][2kt][64]
    const float* __restrict__ bu,
    int E)
{
    __shared__ half8 WL[12 * 2 * 64];   // 24KB
    __shared__ half8 UL[12 * 2 * 64];   // 24KB
    for (int i = threadIdx.x; i < 12 * 2 * 64; i += 256) {
        WL[i] = wWu[i];
        UL[i] = wUu[i];
    }
    __syncthreads();

    const int wid = threadIdx.x >> 6;
    const int lane = threadIdx.x & 63;
    const int e0 = (blockIdx.x * 4 + wid) * 16;
    const int erow = e0 + (lane & 15);
    const int ec = min(erow, E - 1);
    const int hi = lane >> 4;

    // A fragments
    half8 AX[2], AH[2];
    #pragma unroll
    for (int kt = 0; kt < 2; ++kt) {
        const float* ap = agg + (size_t)ec * D + 32 * kt + 8 * hi;
        float4 x0 = *reinterpret_cast<const float4*>(ap);
        float4 x1 = *reinterpret_cast<const float4*>(ap + 4);
        half8 ax;
        ax[0] = (_Float16)x0.x; ax[1] = (_Float16)x0.y;
        ax[2] = (_Float16)x0.z; ax[3] = (_Float16)x0.w;
        ax[4] = (_Float16)x1.x; ax[5] = (_Float16)x1.y;
        ax[6] = (_Float16)x1.z; ax[7] = (_Float16)x1.w;
        AX[kt] = ax;
        AH[kt] = reinterpret_cast<const half8*>(h16 + (size_t)ec * D)[4 * kt + hi];
    }

    f32x4 az[4], ar_[4], acx[4], ach[4];
    #pragma unroll
    for (int i = 0; i < 4; ++i) {
        az[i] = (f32x4){0.f, 0.f, 0.f, 0.f};
        ar_[i] = (f32x4){0.f, 0.f, 0.f, 0.f};
        acx[i] = (f32x4){0.f, 0.f, 0.f, 0.f};
        ach[i] = (f32x4){0.f, 0.f, 0.f, 0.f};
    }

    #pragma unroll
    for (int i = 0; i < 4; ++i) {
        #pragma unroll
        for (int kt = 0; kt < 2; ++kt) {
            az[i]  = __builtin_amdgcn_mfma_f32_16x16x32_f16(AX[kt], WL[((0 + i) * 2 + kt) * 64 + lane], az[i], 0, 0, 0);
            az[i]  = __builtin_amdgcn_mfma_f32_16x16x32_f16(AH[kt], UL[((0 + i) * 2 + kt) * 64 + lane], az[i], 0, 0, 0);
            ar_[i] = __builtin_amdgcn_mfma_f32_16x16x32_f16(AX[kt], WL[((4 + i) * 2 + kt) * 64 + lane], ar_[i], 0, 0, 0);
            ar_[i] = __builtin_amdgcn_mfma_f32_16x16x32_f16(AH[kt], UL[((4 + i) * 2 + kt) * 64 + lane], ar_[i], 0, 0, 0);
            acx[i] = __builtin_amdgcn_mfma_f32_16x16x32_f16(AX[kt], WL[((8 + i) * 2 + kt) * 64 + lane], acx[i], 0, 0, 0);
            ach[i] = __builtin_amdgcn_mfma_f32_16x16x32_f16(AH[kt], UL[((8 + i) * 2 + kt) * 64 + lane], ach[i], 0, 0, 0);
        }
    }

    // epilogue: GRU nonlinearity; write h32/h16; zero agg
    #pragma unroll
    for (int i = 0; i < 4; ++i) {
        int n = 16 * i + (lane & 15);
        float bz = bu[n] + bu[192 + n];
        float br_ = bu[64 + n] + bu[256 + n];
        float bx = bu[128 + n];
        float bh = bu[320 + n];
        #pragma unroll
        for (int r = 0; r < 4; ++r) {
            int e = e0 + hi * 4 + r;
            if (e < E) {
                float z = fast_sig(az[i][r] + bz);
                float rr = fast_sig(ar_[i][r] + br_);
                float c = fast_tanh(acx[i][r] + bx + rr * (ach[i][r] + bh));
                float hp = h32[(size_t)e * D + n];
                float hn = z * hp + (1.0f - z) * c;
                h32[(size_t)e * D + n] = hn;
                h16[(size_t)e * D + n] = (_Float16)hn;
                agg[(size_t)e * D + n] = 0.0f;
            }
        }
    }
}

// ---------------------------------------------------------------------------
// Readout GRU (fp16 MFMA): wave = 16 edges, blockIdx.y = column half (64 cols).
// x = h16 (current mp state), state in fp16 double buffer.
// ---------------------------------------------------------------------------
__global__ __launch_bounds__(256) void ro_mfma(
    const _Float16* __restrict__ h16,
    const _Float16* __restrict__ hin,
    _Float16* __restrict__ hout,
    const half8* __restrict__ wWr,  // [24nt][2kt][64]
    const half8* __restrict__ wUr,  // [24nt][4kt][64]
    const float* __restrict__ br,
    int E)
{
    const int ch = blockIdx.y;
    __shared__ half8 WL[12 * 2 * 64];   // 24KB
    __shared__ half8 UL[12 * 4 * 64];   // 48KB

    for (int idx = threadIdx.x; idx < 12 * 2 * 64; idx += 256) {
        int lane_ = idx & 63;
        int kt = (idx >> 6) & 1;
        int lt = idx >> 7;
        int g = lt >> 2, i = lt & 3;
        int ntg = 8 * g + 4 * ch + i;
        WL[idx] = wWr[(ntg * 2 + kt) * 64 + lane_];
    }
    for (int idx = threadIdx.x; idx < 12 * 4 * 64; idx += 256) {
        int lane_ = idx & 63;
        int kt = (idx >> 6) & 3;
        int lt = idx >> 8;
        int g = lt >> 2, i = lt & 3;
        int ntg = 8 * g + 4 * ch + i;
        UL[idx] = wUr[(ntg * 4 + kt) * 64 + lane_];
    }
    __syncthreads();

    const int wid = threadIdx.x >> 6;
    const int lane = threadIdx.x & 63;
    const int e0 = (blockIdx.x * 4 + wid) * 16;
    const int erow = e0 + (lane & 15);
    const int ec = min(erow, E - 1);
    const int hi = lane >> 4;

    half8 AX[2], AH[4];
    #pragma unroll
    for (int kt = 0; kt < 2; ++kt)
        AX[kt] = reinterpret_cast<const half8*>(h16 + (size_t)ec * D)[4 * kt + hi];
    #pragma unroll
    for (int kt = 0; kt < 4; ++kt)
        AH[kt] = reinterpret_cast<const half8*>(hin + (size_t)ec * R)[4 * kt + hi];

    f32x4 az[4], ar_[4], acx[4], ach[4];
    #pragma unroll
    for (int i = 0; i < 4; ++i) {
        az[i] = (f32x4){0.f, 0.f, 0.f, 0.f};
        ar_[i] = (f32x4){0.f, 0.f, 0.f, 0.f};
        acx[i] = (f32x4){0.f, 0.f, 0.f, 0.f};
        ach[i] = (f32x4){0.f, 0.f, 0.f, 0.f};
    }

    #pragma unroll
    for (int i = 0; i < 4; ++i) {
        #pragma unroll
        for (int kt = 0; kt < 2; ++kt) {
            az[i]  = __builtin_amdgcn_mfma_f32_16x16x32_f16(AX[kt], WL[((0 + i) * 2 + kt) * 64 + lane], az[i], 0, 0, 0);
            ar_[i] = __builtin_amdgcn_mfma_f32_16x16x32_f16(AX[kt], WL[((4 + i) * 2 + kt) * 64 + lane], ar_[i], 0, 0, 0);
            acx[i] = __builtin_amdgcn_mfma_f32_16x16x32_f16(AX[kt], WL[((8 + i) * 2 + kt) * 64 + lane], acx[i], 0, 0, 0);
        }
        #pragma unroll
        for (int kt = 0; kt < 4; ++kt) {
            az[i]  = __builtin_amdgcn_mfma_f32_16x16x32_f16(AH[kt], UL[((0 + i) * 4 + kt) * 64 + lane], az[i], 0, 0, 0);
            ar_[i] = __builtin_amdgcn_mfma_f32_16x16x32_f16(AH[kt], UL[((4 + i) * 4 + kt) * 64 + lane], ar_[i], 0, 0, 0);
            ach[i] = __builtin_amdgcn_mfma_f32_16x16x32_f16(AH[kt], UL[((8 + i) * 4 + kt) * 64 + lane], ach[i], 0, 0, 0);
        }
    }

    #pragma unroll
    for (int i = 0; i < 4; ++i) {
        int c = 64 * ch + 16 * i + (lane & 15);
        float bz = br[c] + br[384 + c];
        float br_ = br[128 + c] + br[512 + c];
        float bx = br[256 + c];
        float bh = br[640 + c];
        #pragma unroll
        for (int r = 0; r < 4; ++r) {
            int e = e0 + hi * 4 + r;
            if (e < E) {
                float z = fast_sig(az[i][r] + bz);
                float rr = fast_sig(ar_[i][r] + br_);
                float cc = fast_tanh(acx[i][r] + bx + rr * (ach[i][r] + bh));
                float hp = (float)hin[(size_t)e * R + c];
                hout[(size_t)e * R + c] = (_Float16)(z * hp + (1.0f - z) * cc);
            }
        }
    }
}

// ---------------------------------------------------------------------------
// Output: out[g] = b_out + sum_{e: gid[e]==g} dot(hro[e], W_out)
// ---------------------------------------------------------------------------
__global__ void out_init_kernel(float* __restrict__ out, const float* __restrict__ b_out, int G) {
    int g = blockIdx.x * blockDim.x + threadIdx.x;
    if (g < G) out[g] = b_out[0];
}

__global__ __launch_bounds__(256) void out_kernel(
    const _Float16* __restrict__ hro,
    const int* __restrict__ gid,
    const float* __restrict__ Wout,
    float* __restrict__ out,
    int E)
{
    int e = blockIdx.x * 256 + threadIdx.x;
    if (e >= E) return;
    const half8* hp = reinterpret_cast<const half8*>(hro + (size_t)e * R);
    float s = 0.0f;
    #pragma unroll
    for (int kk = 0; kk < R / 8; ++kk) {
        half8 v = hp[kk];
        #pragma unroll
        for (int j = 0; j < 8; ++j)
            s = fmaf((float)v[j], Wout[kk * 8 + j], s);
    }
    unsafeAtomicAdd(out + gid[e], s);
}

// ---------------------------------------------------------------------------
extern "C" void kernel_launch(void* const* d_in, const int* in_sizes, int n_in,
                              void* d_out, int out_size, void* d_ws, size_t ws_size,
                              hipStream_t stream) {
    const float* link_state = (const float*)d_in[0];
    const int*   first      = (const int*)d_in[1];
    const int*   second     = (const int*)d_in[2];
    const int*   gids       = (const int*)d_in[3];
    const float* Wm         = (const float*)d_in[5];
    const float* bm         = (const float*)d_in[6];
    const float* Wu         = (const float*)d_in[7];
    const float* Uu         = (const float*)d_in[8];
    const float* bu         = (const float*)d_in[9];
    const float* Wr         = (const float*)d_in[10];
    const float* Ur         = (const float*)d_in[11];
    const float* brb        = (const float*)d_in[12];
    const float* Wout       = (const float*)d_in[13];
    const float* bout       = (const float*)d_in[14];

    const int E = in_sizes[0] / D;
    const int M = in_sizes[1];
    const int G = out_size;

    char* p = (char*)d_ws;
    auto carve = [&](size_t bytes) {
        void* r = (void*)p;
        p += (bytes + 255) & ~(size_t)255;
        return r;
    };
    float*     h32  = (float*)carve((size_t)E * D * 4);
    _Float16*  h16  = (_Float16*)carve((size_t)E * D * 2);
    float*     agg  = (float*)carve((size_t)E * D * 4);
    _Float16*  hroA = (_Float16*)carve((size_t)E * R * 2);
    _Float16*  hroB = (_Float16*)carve((size_t)E * R * 2);
    int*       perm = (int*)carve((size_t)M * 4);
    int*       cnt  = (int*)carve((size_t)E * 4);
    int*       cur  = (int*)carve((size_t)E * 4);
    int*       off  = (int*)carve((size_t)(E + 1) * 4);
    _Float16*  wWm  = (_Float16*)carve(8192 * 2);
    _Float16*  wWu  = (_Float16*)carve(12288 * 2);
    _Float16*  wUu  = (_Float16*)carve(12288 * 2);
    _Float16*  wWr  = (_Float16*)carve(24576 * 2);
    _Float16*  wUr  = (_Float16*)carve(49152 * 2);

    hipMemcpyAsync(h32, link_state, (size_t)E * D * 4, hipMemcpyDeviceToDevice, stream);
    hipMemsetAsync(agg, 0, (size_t)E * D * 4, stream);
    hipMemsetAsync(hroA, 0, (size_t)E * R * 2, stream);
    hipMemsetAsync(cnt, 0, (size_t)E * 4, stream);
    hipMemsetAsync(cur, 0, (size_t)E * 4, stream);

    h16_init<<<(E * D + 255) / 256, 256, 0, stream>>>(link_state, h16, E * D);
    swizzle_w<<<(8192 + 255) / 256, 256, 0, stream>>>(Wm, wWm, 128, 64);
    swizzle_w<<<(12288 + 255) / 256, 256, 0, stream>>>(Wu, wWu, 64, 192);
    swizzle_w<<<(12288 + 255) / 256, 256, 0, stream>>>(Uu, wUu, 64, 192);
    swizzle_w<<<(24576 + 255) / 256, 256, 0, stream>>>(Wr, wWr, 64, 384);
    swizzle_w<<<(49152 + 255) / 256, 256, 0, stream>>>(Ur, wUr, 128, 384);

    hist_kernel<<<(M + 255) / 256, 256, 0, stream>>>(second, cnt, M);
    scan_kernel<<<1, 1024, 0, stream>>>(cnt, off, E);
    scatter_kernel<<<(M + 255) / 256, 256, 0, stream>>>(second, off, cur, perm, M);

    const int msg_blocks = (M + 63) / 64;
    const int e_blocks = (E + 63) / 64;

    _Float16* rin = hroA;
    _Float16* rout = hroB;
    for (int t = 0; t < NSTEPS; ++t) {
        msg_mfma<<<msg_blocks, 256, 0, stream>>>(h16, first, second, perm,
                                                 (const half8*)wWm, bm, agg, M);
        upd_mfma<<<e_blocks, 256, 0, stream>>>(agg, h32, h16,
                                               (const half8*)wWu, (const half8*)wUu, bu, E);
        ro_mfma<<<dim3(e_blocks, 2), 256, 0, stream>>>(h16, rin, rout,
                                                       (const half8*)wWr, (const half8*)wUr, brb, E);
        _Float16* tmp = rin; rin = rout; rout = tmp;
    }

    out_init_kernel<<<(G + 255) / 256, 256, 0, stream>>>((float*)d_out, bout, G);
    out_kernel<<<(E + 255) / 256, 256, 0, stream>>>(rin, gids, Wout, (float*)d_out, E);
}

// Round 4
// 1247.585 us; speedup vs baseline: 17.0986x; 1.2102x over previous
//
#include <hip/hip_runtime.h>
#include <hip/hip_bf16.h>

#define D 64
#define R 128
#define NSTEPS 8
#define SELU_SCALE 1.0507009873554805f
#define SELU_ALPHA 1.6732632423543772f

typedef _Float16 half8 __attribute__((ext_vector_type(8)));
typedef float f32x4 __attribute__((ext_vector_type(4)));

__device__ __forceinline__ float fast_sig(float x) {
    return __fdividef(1.0f, 1.0f + __expf(-x));
}
__device__ __forceinline__ float fast_tanh(float x) {
    float xc = fminf(fmaxf(x, -15.0f), 15.0f);
    float e = __expf(2.0f * xc);
    return 1.0f - __fdividef(2.0f, e + 1.0f);
}

// ---------------------------------------------------------------------------
// Prep: all 5 weight swizzles in ONE kernel. fp32 [K][N] -> fp16 MFMA
// B-fragment order: dst[((nt*KT+kt)*64+lane)*8+j] =
//   src[(32*kt + 8*(lane>>4) + j)*N + 16*nt + (lane&15)]
// ---------------------------------------------------------------------------
__global__ __launch_bounds__(256) void swizzle_all(
    const float* __restrict__ Wm, const float* __restrict__ Wu,
    const float* __restrict__ Uu, const float* __restrict__ Wr,
    const float* __restrict__ Ur,
    _Float16* __restrict__ wWm, _Float16* __restrict__ wWu,
    _Float16* __restrict__ wUu, _Float16* __restrict__ wWr,
    _Float16* __restrict__ wUr)
{
    const float* src; _Float16* dst; int K, N;
    switch (blockIdx.y) {
        case 0: src = Wm; dst = wWm; K = 128; N = 64;  break;
        case 1: src = Wu; dst = wWu; K = 64;  N = 192; break;
        case 2: src = Uu; dst = wUu; K = 64;  N = 192; break;
        case 3: src = Wr; dst = wWr; K = 64;  N = 384; break;
        default: src = Ur; dst = wUr; K = 128; N = 384; break;
    }
    int idx = blockIdx.x * 256 + threadIdx.x;
    int KT = K >> 5;
    int total = KT * (N >> 4) * 512;
    if (idx >= total) return;
    int j = idx & 7;
    int lane = (idx >> 3) & 63;
    int kt = (idx >> 9) % KT;
    int nt = idx / (512 * KT);
    int k = 32 * kt + 8 * (lane >> 4) + j;
    int n = 16 * nt + (lane & 15);
    dst[idx] = (_Float16)src[(size_t)k * N + n];
}

__global__ __launch_bounds__(256) void h16_init(const float* __restrict__ src,
                                                _Float16* __restrict__ dst, int n) {
    int i = blockIdx.x * 256 + threadIdx.x;
    if (i < n) dst[i] = (_Float16)src[i];
}

// ---------------------------------------------------------------------------
// CSR build: hist -> 3-kernel scan -> scatter -> fs pack
// ---------------------------------------------------------------------------
__global__ __launch_bounds__(256) void hist_kernel(const int* __restrict__ second,
                                                   int* __restrict__ cnt, int M) {
    int m = blockIdx.x * 256 + threadIdx.x;
    if (m < M) atomicAdd(&cnt[second[m]], 1);
}

__global__ __launch_bounds__(256) void scan_bsum(const int* __restrict__ cnt,
                                                 int* __restrict__ bsum, int E) {
    int i = blockIdx.x * 256 + threadIdx.x;
    int tid = threadIdx.x;
    int v = (i < E) ? cnt[i] : 0;
    __shared__ int s[256];
    s[tid] = v;
    __syncthreads();
    #pragma unroll
    for (int d = 1; d < 256; d <<= 1) {
        int t = (tid >= d) ? s[tid - d] : 0;
        __syncthreads();
        s[tid] += t;
        __syncthreads();
    }
    if (tid == 255) bsum[blockIdx.x] = s[255];
}

__global__ __launch_bounds__(1024) void scan_part(int* __restrict__ bsum, int NB) {
    int tid = threadIdx.x;
    __shared__ int s[1024];
    int v = (tid < NB) ? bsum[tid] : 0;
    s[tid] = v;
    __syncthreads();
    #pragma unroll
    for (int d = 1; d < 1024; d <<= 1) {
        int t = (tid >= d) ? s[tid - d] : 0;
        __syncthreads();
        s[tid] += t;
        __syncthreads();
    }
    if (tid < NB) bsum[tid] = s[tid] - v;   // exclusive
}

__global__ __launch_bounds__(256) void scan_final(const int* __restrict__ cnt,
                                                  const int* __restrict__ bsum,
                                                  int* __restrict__ off, int E) {
    int i = blockIdx.x * 256 + threadIdx.x;
    int tid = threadIdx.x;
    int v = (i < E) ? cnt[i] : 0;
    __shared__ int s[256];
    s[tid] = v;
    __syncthreads();
    #pragma unroll
    for (int d = 1; d < 256; d <<= 1) {
        int t = (tid >= d) ? s[tid - d] : 0;
        __syncthreads();
        s[tid] += t;
        __syncthreads();
    }
    if (i < E) off[i] = bsum[blockIdx.x] + s[tid] - v;
}

__global__ __launch_bounds__(256) void scatter_kernel(const int* __restrict__ second,
                                                      const int* __restrict__ off,
                                                      int* __restrict__ cur,
                                                      int* __restrict__ perm, int M) {
    int m = blockIdx.x * 256 + threadIdx.x;
    if (m < M) {
        int s = second[m];
        int p = atomicAdd(&cur[s], 1);
        perm[off[s] + p] = m;
    }
}

__global__ __launch_bounds__(256) void fs_pack(const int* __restrict__ first,
                                               const int* __restrict__ second,
                                               const int* __restrict__ perm,
                                               int2* __restrict__ fs, int M) {
    int m = blockIdx.x * 256 + threadIdx.x;
    if (m < M) {
        int pm = perm[m];
        fs[m] = make_int2(first[pm], second[pm]);
    }
}

// ---------------------------------------------------------------------------
// Message kernel (fp16 MFMA): wave = 16 messages in receiver-sorted order.
// msg = selu([h[f],h[s]] @ Wm + bm); segmented run-sum -> contiguous
// 256B atomic bursts into agg (f32). Weights fully register-resident.
// ---------------------------------------------------------------------------
__global__ __launch_bounds__(256) void msg_mfma(
    const _Float16* __restrict__ h16,
    const int2* __restrict__ fs,
    const half8* __restrict__ wB,   // [4nt][4kt][64] half8
    const float* __restrict__ bm,
    float* __restrict__ agg, int M)
{
    __shared__ float tile[4][16][64];
    __shared__ int skey[4][16];

    const int wid = threadIdx.x >> 6;
    const int lane = threadIdx.x & 63;
    const int t0 = (blockIdx.x * 4 + wid) * 16;

    half8 B[4][4];
    #pragma unroll
    for (int nt = 0; nt < 4; ++nt)
        #pragma unroll
        for (int kt = 0; kt < 4; ++kt)
            B[nt][kt] = wB[(nt * 4 + kt) * 64 + lane];

    int row = t0 + (lane & 15);
    bool rowv = (row < M);
    int2 p = fs[min(row, M - 1)];
    int fi = p.x, si = p.y;

    const half8* fr = reinterpret_cast<const half8*>(h16 + (size_t)fi * D);
    const half8* sr = reinterpret_cast<const half8*>(h16 + (size_t)si * D);
    const int hi = lane >> 4;
    half8 A[4];
    A[0] = fr[hi];
    A[1] = fr[4 + hi];
    A[2] = sr[hi];
    A[3] = sr[4 + hi];

    f32x4 acc[4];
    #pragma unroll
    for (int nt = 0; nt < 4; ++nt) acc[nt] = (f32x4){0.f, 0.f, 0.f, 0.f};

    #pragma unroll
    for (int nt = 0; nt < 4; ++nt)
        #pragma unroll
        for (int kt = 0; kt < 4; ++kt)
            acc[nt] = __builtin_amdgcn_mfma_f32_16x16x32_f16(A[kt], B[nt][kt], acc[nt], 0, 0, 0);

    #pragma unroll
    for (int nt = 0; nt < 4; ++nt) {
        int n = nt * 16 + (lane & 15);
        float bias = bm[n];
        #pragma unroll
        for (int r = 0; r < 4; ++r) {
            float v = acc[nt][r] + bias;
            v = (v > 0.0f) ? (SELU_SCALE * v)
                           : (SELU_SCALE * SELU_ALPHA) * (__expf(v) - 1.0f);
            tile[wid][hi * 4 + r][n] = v;
        }
    }
    if (lane < 16) skey[wid][lane] = rowv ? si : -1;
    __syncthreads();

    float run = 0.0f;
    int kprev = skey[wid][0];
    #pragma unroll
    for (int m = 0; m < 16; ++m) {
        int km = skey[wid][m];
        if (km != kprev) {
            if (kprev >= 0) unsafeAtomicAdd(agg + (size_t)kprev * D + lane, run);
            run = 0.0f;
            kprev = km;
        }
        run += tile[wid][m][lane];
    }
    if (kprev >= 0) unsafeAtomicAdd(agg + (size_t)kprev * D + lane, run);
}

// ---------------------------------------------------------------------------
// Update GRU (fp16 MFMA): wave = 32 edges (2 groups of 16); B-fragments
// loaded into registers per output tile i, shared across both groups.
// ---------------------------------------------------------------------------
__global__ __launch_bounds__(256) void upd_mfma(
    float* __restrict__ agg,
    float* __restrict__ h32,
    _Float16* __restrict__ h16,
    const half8* __restrict__ wWu,  // [12nt][2kt][64]
    const half8* __restrict__ wUu,  // [12nt][2kt][64]
    const float* __restrict__ bu,
    int E)
{
    __shared__ half8 WL[12 * 2 * 64];   // 24KB
    __shared__ half8 UL[12 * 2 * 64];   // 24KB
    for (int i = threadIdx.x; i < 12 * 2 * 64; i += 256) {
        WL[i] = wWu[i];
        UL[i] = wUu[i];
    }
    __syncthreads();

    const int wid = threadIdx.x >> 6;
    const int lane = threadIdx.x & 63;
    const int hi = lane >> 4;
    const int e0 = (blockIdx.x * 4 + wid) * 32;

    half8 AX[2][2], AH[2][2];
    #pragma unroll
    for (int g = 0; g < 2; ++g) {
        int ec = min(e0 + g * 16 + (lane & 15), E - 1);
        #pragma unroll
        for (int kt = 0; kt < 2; ++kt) {
            const float* ap = agg + (size_t)ec * D + 32 * kt + 8 * hi;
            float4 x0 = *reinterpret_cast<const float4*>(ap);
            float4 x1 = *reinterpret_cast<const float4*>(ap + 4);
            half8 ax;
            ax[0] = (_Float16)x0.x; ax[1] = (_Float16)x0.y;
            ax[2] = (_Float16)x0.z; ax[3] = (_Float16)x0.w;
            ax[4] = (_Float16)x1.x; ax[5] = (_Float16)x1.y;
            ax[6] = (_Float16)x1.z; ax[7] = (_Float16)x1.w;
            AX[g][kt] = ax;
            AH[g][kt] = reinterpret_cast<const half8*>(h16 + (size_t)ec * D)[4 * kt + hi];
        }
    }

    #pragma unroll
    for (int i = 0; i < 4; ++i) {
        half8 WBz[2], WBr[2], WBc[2], UBz[2], UBr[2], UBc[2];
        #pragma unroll
        for (int kt = 0; kt < 2; ++kt) {
            WBz[kt] = WL[((0 + i) * 2 + kt) * 64 + lane];
            WBr[kt] = WL[((4 + i) * 2 + kt) * 64 + lane];
            WBc[kt] = WL[((8 + i) * 2 + kt) * 64 + lane];
            UBz[kt] = UL[((0 + i) * 2 + kt) * 64 + lane];
            UBr[kt] = UL[((4 + i) * 2 + kt) * 64 + lane];
            UBc[kt] = UL[((8 + i) * 2 + kt) * 64 + lane];
        }
        int n = 16 * i + (lane & 15);
        float bz  = bu[n] + bu[192 + n];
        float brr = bu[64 + n] + bu[256 + n];
        float bx  = bu[128 + n];
        float bh  = bu[320 + n];

        #pragma unroll
        for (int g = 0; g < 2; ++g) {
            f32x4 az  = (f32x4){0.f, 0.f, 0.f, 0.f};
            f32x4 ar_ = (f32x4){0.f, 0.f, 0.f, 0.f};
            f32x4 acx = (f32x4){0.f, 0.f, 0.f, 0.f};
            f32x4 ach = (f32x4){0.f, 0.f, 0.f, 0.f};
            #pragma unroll
            for (int kt = 0; kt < 2; ++kt) {
                az  = __builtin_amdgcn_mfma_f32_16x16x32_f16(AX[g][kt], WBz[kt], az, 0, 0, 0);
                az  = __builtin_amdgcn_mfma_f32_16x16x32_f16(AH[g][kt], UBz[kt], az, 0, 0, 0);
                ar_ = __builtin_amdgcn_mfma_f32_16x16x32_f16(AX[g][kt], WBr[kt], ar_, 0, 0, 0);
                ar_ = __builtin_amdgcn_mfma_f32_16x16x32_f16(AH[g][kt], UBr[kt], ar_, 0, 0, 0);
                acx = __builtin_amdgcn_mfma_f32_16x16x32_f16(AX[g][kt], WBc[kt], acx, 0, 0, 0);
                ach = __builtin_amdgcn_mfma_f32_16x16x32_f16(AH[g][kt], UBc[kt], ach, 0, 0, 0);
            }
            #pragma unroll
            for (int r = 0; r < 4; ++r) {
                int e = e0 + g * 16 + hi * 4 + r;
                if (e < E) {
                    float z = fast_sig(az[r] + bz);
                    float rr = fast_sig(ar_[r] + brr);
                    float c = fast_tanh(acx[r] + bx + rr * (ach[r] + bh));
                    float hp = h32[(size_t)e * D + n];
                    float hn = z * hp + (1.0f - z) * c;
                    h32[(size_t)e * D + n] = hn;
                    h16[(size_t)e * D + n] = (_Float16)hn;
                    agg[(size_t)e * D + n] = 0.0f;
                }
            }
        }
    }
}

// ---------------------------------------------------------------------------
// Readout GRU (fp16 MFMA): wave = 32 edges (2 groups), blockIdx.y = col half.
// B-fragments register-cached per tile i, shared across groups.
// ---------------------------------------------------------------------------
__global__ __launch_bounds__(256) void ro_mfma(
    const _Float16* __restrict__ h16,
    const _Float16* __restrict__ hin,
    _Float16* __restrict__ hout,
    const half8* __restrict__ wWr,  // [24nt][2kt][64]
    const half8* __restrict__ wUr,  // [24nt][4kt][64]
    const float* __restrict__ br,
    int E)
{
    const int ch = blockIdx.y;
    __shared__ half8 WL[12 * 2 * 64];   // 24KB
    __shared__ half8 UL[12 * 4 * 64];   // 48KB

    for (int idx = threadIdx.x; idx < 12 * 2 * 64; idx += 256) {
        int lane_ = idx & 63;
        int kt = (idx >> 6) & 1;
        int lt = idx >> 7;
        int g = lt >> 2, i = lt & 3;
        int ntg = 8 * g + 4 * ch + i;
        WL[idx] = wWr[(ntg * 2 + kt) * 64 + lane_];
    }
    for (int idx = threadIdx.x; idx < 12 * 4 * 64; idx += 256) {
        int lane_ = idx & 63;
        int kt = (idx >> 6) & 3;
        int lt = idx >> 8;
        int g = lt >> 2, i = lt & 3;
        int ntg = 8 * g + 4 * ch + i;
        UL[idx] = wUr[(ntg * 4 + kt) * 64 + lane_];
    }
    __syncthreads();

    const int wid = threadIdx.x >> 6;
    const int lane = threadIdx.x & 63;
    const int hi = lane >> 4;
    const int e0 = (blockIdx.x * 4 + wid) * 32;

    half8 AX[2][2], AH[2][4];
    #pragma unroll
    for (int g = 0; g < 2; ++g) {
        int ec = min(e0 + g * 16 + (lane & 15), E - 1);
        #pragma unroll
        for (int kt = 0; kt < 2; ++kt)
            AX[g][kt] = reinterpret_cast<const half8*>(h16 + (size_t)ec * D)[4 * kt + hi];
        #pragma unroll
        for (int kt = 0; kt < 4; ++kt)
            AH[g][kt] = reinterpret_cast<const half8*>(hin + (size_t)ec * R)[4 * kt + hi];
    }

    #pragma unroll
    for (int i = 0; i < 4; ++i) {
        half8 WBz[2], WBr[2], WBx[2], UBz[4], UBr[4], UBh[4];
        #pragma unroll
        for (int kt = 0; kt < 2; ++kt) {
            WBz[kt] = WL[((0 + i) * 2 + kt) * 64 + lane];
            WBr[kt] = WL[((4 + i) * 2 + kt) * 64 + lane];
            WBx[kt] = WL[((8 + i) * 2 + kt) * 64 + lane];
        }
        #pragma unroll
        for (int kt = 0; kt < 4; ++kt) {
            UBz[kt] = UL[((0 + i) * 4 + kt) * 64 + lane];
            UBr[kt] = UL[((4 + i) * 4 + kt) * 64 + lane];
            UBh[kt] = UL[((8 + i) * 4 + kt) * 64 + lane];
        }
        int c = 64 * ch + 16 * i + (lane & 15);
        float bz  = br[c] + br[384 + c];
        float brr = br[128 + c] + br[512 + c];
        float bx  = br[256 + c];
        float bh  = br[640 + c];

        #pragma unroll
        for (int g = 0; g < 2; ++g) {
            f32x4 az  = (f32x4){0.f, 0.f, 0.f, 0.f};
            f32x4 ar_ = (f32x4){0.f, 0.f, 0.f, 0.f};
            f32x4 acx = (f32x4){0.f, 0.f, 0.f, 0.f};
            f32x4 ach = (f32x4){0.f, 0.f, 0.f, 0.f};
            #pragma unroll
            for (int kt = 0; kt < 2; ++kt) {
                az  = __builtin_amdgcn_mfma_f32_16x16x32_f16(AX[g][kt], WBz[kt], az, 0, 0, 0);
                ar_ = __builtin_amdgcn_mfma_f32_16x16x32_f16(AX[g][kt], WBr[kt], ar_, 0, 0, 0);
                acx = __builtin_amdgcn_mfma_f32_16x16x32_f16(AX[g][kt], WBx[kt], acx, 0, 0, 0);
            }
            #pragma unroll
            for (int kt = 0; kt < 4; ++kt) {
                az  = __builtin_amdgcn_mfma_f32_16x16x32_f16(AH[g][kt], UBz[kt], az, 0, 0, 0);
                ar_ = __builtin_amdgcn_mfma_f32_16x16x32_f16(AH[g][kt], UBr[kt], ar_, 0, 0, 0);
                ach = __builtin_amdgcn_mfma_f32_16x16x32_f16(AH[g][kt], UBh[kt], ach, 0, 0, 0);
            }
            #pragma unroll
            for (int r = 0; r < 4; ++r) {
                int e = e0 + g * 16 + hi * 4 + r;
                if (e < E) {
                    float z = fast_sig(az[r] + bz);
                    float rr = fast_sig(ar_[r] + brr);
                    float cc = fast_tanh(acx[r] + bx + rr * (ach[r] + bh));
                    float hp = (float)hin[(size_t)e * R + c];
                    hout[(size_t)e * R + c] = (_Float16)(z * hp + (1.0f - z) * cc);
                }
            }
        }
    }
}

// ---------------------------------------------------------------------------
// Output: out[g] = b_out + sum_{e: gid[e]==g} dot(hro[e], W_out)
// gids sorted -> wave-level segmented scan; invalid lanes carry sentinel
// g=-1 so the final valid segment always sees a key change and flushes.
// ---------------------------------------------------------------------------
__global__ void out_init_kernel(float* __restrict__ out, const float* __restrict__ b_out, int G) {
    int g = blockIdx.x * blockDim.x + threadIdx.x;
    if (g < G) out[g] = b_out[0];
}

__global__ __launch_bounds__(256) void out_kernel(
    const _Float16* __restrict__ hro,
    const int* __restrict__ gid,
    const float* __restrict__ Wout,
    float* __restrict__ out,
    int E)
{
    int e = blockIdx.x * 256 + threadIdx.x;
    int lane = threadIdx.x & 63;
    int ec = min(e, E - 1);
    const half8* hp = reinterpret_cast<const half8*>(hro + (size_t)ec * R);
    float s = 0.0f;
    #pragma unroll
    for (int kk = 0; kk < R / 8; ++kk) {
        half8 v = hp[kk];
        #pragma unroll
        for (int j = 0; j < 8; ++j)
            s = fmaf((float)v[j], Wout[kk * 8 + j], s);
    }
    bool valid = (e < E);
    if (!valid) s = 0.0f;
    int g = valid ? gid[ec] : -1;           // sentinel for OOB lanes
    // wave-level inclusive segmented scan by key
    #pragma unroll
    for (int d = 1; d < 64; d <<= 1) {
        float t = __shfl_up(s, d);
        int kg = __shfl_up(g, d);
        if (lane >= d && kg == g) s += t;
    }
    int gnext = __shfl_down(g, 1);
    bool tail = (lane == 63) || (gnext != g);
    if (tail && valid) unsafeAtomicAdd(out + g, s);
}

// ---------------------------------------------------------------------------
extern "C" void kernel_launch(void* const* d_in, const int* in_sizes, int n_in,
                              void* d_out, int out_size, void* d_ws, size_t ws_size,
                              hipStream_t stream) {
    const float* link_state = (const float*)d_in[0];
    const int*   first      = (const int*)d_in[1];
    const int*   second     = (const int*)d_in[2];
    const int*   gids       = (const int*)d_in[3];
    const float* Wm         = (const float*)d_in[5];
    const float* bm         = (const float*)d_in[6];
    const float* Wu         = (const float*)d_in[7];
    const float* Uu         = (const float*)d_in[8];
    const float* bu         = (const float*)d_in[9];
    const float* Wr         = (const float*)d_in[10];
    const float* Ur         = (const float*)d_in[11];
    const float* brb        = (const float*)d_in[12];
    const float* Wout       = (const float*)d_in[13];
    const float* bout       = (const float*)d_in[14];

    const int E = in_sizes[0] / D;
    const int M = in_sizes[1];
    const int G = out_size;

    char* p = (char*)d_ws;
    auto carve = [&](size_t bytes) {
        void* r = (void*)p;
        p += (bytes + 255) & ~(size_t)255;
        return r;
    };
    float*     h32  = (float*)carve((size_t)E * D * 4);
    _Float16*  h16  = (_Float16*)carve((size_t)E * D * 2);
    float*     agg  = (float*)carve((size_t)E * D * 4);
    _Float16*  hroA = (_Float16*)carve((size_t)E * R * 2);
    _Float16*  hroB = (_Float16*)carve((size_t)E * R * 2);
    int*       perm = (int*)carve((size_t)M * 4);
    int2*      fs   = (int2*)carve((size_t)M * 8);
    int*       cnt  = (int*)carve((size_t)E * 4);
    int*       cur  = (int*)carve((size_t)E * 4);
    int*       off  = (int*)carve((size_t)(E + 1) * 4);
    int*       bsum = (int*)carve(4096 * 4);
    _Float16*  wWm  = (_Float16*)carve(8192 * 2);
    _Float16*  wWu  = (_Float16*)carve(12288 * 2);
    _Float16*  wUu  = (_Float16*)carve(12288 * 2);
    _Float16*  wWr  = (_Float16*)carve(24576 * 2);
    _Float16*  wUr  = (_Float16*)carve(49152 * 2);

    hipMemcpyAsync(h32, link_state, (size_t)E * D * 4, hipMemcpyDeviceToDevice, stream);
    hipMemsetAsync(agg, 0, (size_t)E * D * 4, stream);
    hipMemsetAsync(hroA, 0, (size_t)E * R * 2, stream);
    hipMemsetAsync(cnt, 0, (size_t)E * 4, stream);
    hipMemsetAsync(cur, 0, (size_t)E * 4, stream);

    h16_init<<<(E * D + 255) / 256, 256, 0, stream>>>(link_state, h16, E * D);
    swizzle_all<<<dim3(192, 5), 256, 0, stream>>>(Wm, Wu, Uu, Wr, Ur,
                                                  wWm, wWu, wUu, wWr, wUr);

    const int NB = (E + 255) / 256;   // 391 for E=100k; scan_part handles <=1024
    hist_kernel<<<(M + 255) / 256, 256, 0, stream>>>(second, cnt, M);
    scan_bsum<<<NB, 256, 0, stream>>>(cnt, bsum, E);
    scan_part<<<1, 1024, 0, stream>>>(bsum, NB);
    scan_final<<<NB, 256, 0, stream>>>(cnt, bsum, off, E);
    scatter_kernel<<<(M + 255) / 256, 256, 0, stream>>>(second, off, cur, perm, M);
    fs_pack<<<(M + 255) / 256, 256, 0, stream>>>(first, second, perm, fs, M);

    const int msg_blocks = (M + 63) / 64;
    const int e_blocks = (E + 127) / 128;

    _Float16* rin = hroA;
    _Float16* rout = hroB;
    for (int t = 0; t < NSTEPS; ++t) {
        msg_mfma<<<msg_blocks, 256, 0, stream>>>(h16, fs, (const half8*)wWm, bm, agg, M);
        upd_mfma<<<e_blocks, 256, 0, stream>>>(agg, h32, h16,
                                               (const half8*)wWu, (const half8*)wUu, bu, E);
        ro_mfma<<<dim3(e_blocks, 2), 256, 0, stream>>>(h16, rin, rout,
                                                       (const half8*)wWr, (const half8*)wUr, brb, E);
        _Float16* tmp = rin; rin = rout; rout = tmp;
    }

    out_init_kernel<<<(G + 255) / 256, 256, 0, stream>>>((float*)d_out, bout, G);
    out_kernel<<<(E + 255) / 256, 256, 0, stream>>>(rin, gids, Wout, (float*)d_out, E);
}

// Round 5
// 1188.792 us; speedup vs baseline: 17.9442x; 1.0495x over previous
//
#include <hip/hip_runtime.h>
#include <hip/hip_bf16.h>

#define D 64
#define R 128
#define NSTEPS 8
#define SELU_SCALE 1.0507009873554805f
#define SELU_ALPHA 1.6732632423543772f

typedef _Float16 half8 __attribute__((ext_vector_type(8)));
typedef float f32x4 __attribute__((ext_vector_type(4)));

__device__ __forceinline__ float fast_sig(float x) {
    return __fdividef(1.0f, 1.0f + __expf(-x));
}
__device__ __forceinline__ float fast_tanh(float x) {
    float xc = fminf(fmaxf(x, -15.0f), 15.0f);
    float e = __expf(2.0f * xc);
    return 1.0f - __fdividef(2.0f, e + 1.0f);
}

// ---------------------------------------------------------------------------
// Prep: all 5 weight swizzles in ONE kernel. fp32 [K][N] -> fp16 MFMA
// B-fragment order: dst[((nt*KT+kt)*64+lane)*8+j] =
//   src[(32*kt + 8*(lane>>4) + j)*N + 16*nt + (lane&15)]
// ---------------------------------------------------------------------------
__global__ __launch_bounds__(256) void swizzle_all(
    const float* __restrict__ Wm, const float* __restrict__ Wu,
    const float* __restrict__ Uu, const float* __restrict__ Wr,
    const float* __restrict__ Ur,
    _Float16* __restrict__ wWm, _Float16* __restrict__ wWu,
    _Float16* __restrict__ wUu, _Float16* __restrict__ wWr,
    _Float16* __restrict__ wUr)
{
    const float* src; _Float16* dst; int K, N;
    switch (blockIdx.y) {
        case 0: src = Wm; dst = wWm; K = 128; N = 64;  break;
        case 1: src = Wu; dst = wWu; K = 64;  N = 192; break;
        case 2: src = Uu; dst = wUu; K = 64;  N = 192; break;
        case 3: src = Wr; dst = wWr; K = 64;  N = 384; break;
        default: src = Ur; dst = wUr; K = 128; N = 384; break;
    }
    int idx = blockIdx.x * 256 + threadIdx.x;
    int KT = K >> 5;
    int total = KT * (N >> 4) * 512;
    if (idx >= total) return;
    int j = idx & 7;
    int lane = (idx >> 3) & 63;
    int kt = (idx >> 9) % KT;
    int nt = idx / (512 * KT);
    int k = 32 * kt + 8 * (lane >> 4) + j;
    int n = 16 * nt + (lane & 15);
    dst[idx] = (_Float16)src[(size_t)k * N + n];
}

__global__ __launch_bounds__(256) void h16_init(const float* __restrict__ src,
                                                _Float16* __restrict__ dst, int n) {
    int i = blockIdx.x * 256 + threadIdx.x;
    if (i < n) dst[i] = (_Float16)src[i];
}

// ---------------------------------------------------------------------------
// CSR build: hist -> 3-kernel scan -> scatter -> fs pack
// ---------------------------------------------------------------------------
__global__ __launch_bounds__(256) void hist_kernel(const int* __restrict__ second,
                                                   int* __restrict__ cnt, int M) {
    int m = blockIdx.x * 256 + threadIdx.x;
    if (m < M) atomicAdd(&cnt[second[m]], 1);
}

__global__ __launch_bounds__(256) void scan_bsum(const int* __restrict__ cnt,
                                                 int* __restrict__ bsum, int E) {
    int i = blockIdx.x * 256 + threadIdx.x;
    int tid = threadIdx.x;
    int v = (i < E) ? cnt[i] : 0;
    __shared__ int s[256];
    s[tid] = v;
    __syncthreads();
    #pragma unroll
    for (int d = 1; d < 256; d <<= 1) {
        int t = (tid >= d) ? s[tid - d] : 0;
        __syncthreads();
        s[tid] += t;
        __syncthreads();
    }
    if (tid == 255) bsum[blockIdx.x] = s[255];
}

__global__ __launch_bounds__(1024) void scan_part(int* __restrict__ bsum, int NB) {
    int tid = threadIdx.x;
    __shared__ int s[1024];
    int v = (tid < NB) ? bsum[tid] : 0;
    s[tid] = v;
    __syncthreads();
    #pragma unroll
    for (int d = 1; d < 1024; d <<= 1) {
        int t = (tid >= d) ? s[tid - d] : 0;
        __syncthreads();
        s[tid] += t;
        __syncthreads();
    }
    if (tid < NB) bsum[tid] = s[tid] - v;   // exclusive
}

__global__ __launch_bounds__(256) void scan_final(const int* __restrict__ cnt,
                                                  const int* __restrict__ bsum,
                                                  int* __restrict__ off, int E) {
    int i = blockIdx.x * 256 + threadIdx.x;
    int tid = threadIdx.x;
    int v = (i < E) ? cnt[i] : 0;
    __shared__ int s[256];
    s[tid] = v;
    __syncthreads();
    #pragma unroll
    for (int d = 1; d < 256; d <<= 1) {
        int t = (tid >= d) ? s[tid - d] : 0;
        __syncthreads();
        s[tid] += t;
        __syncthreads();
    }
    if (i < E) off[i] = bsum[blockIdx.x] + s[tid] - v;
}

__global__ __launch_bounds__(256) void scatter_kernel(const int* __restrict__ second,
                                                      const int* __restrict__ off,
                                                      int* __restrict__ cur,
                                                      int* __restrict__ perm, int M) {
    int m = blockIdx.x * 256 + threadIdx.x;
    if (m < M) {
        int s = second[m];
        int p = atomicAdd(&cur[s], 1);
        perm[off[s] + p] = m;
    }
}

__global__ __launch_bounds__(256) void fs_pack(const int* __restrict__ first,
                                               const int* __restrict__ second,
                                               const int* __restrict__ perm,
                                               int2* __restrict__ fs, int M) {
    int m = blockIdx.x * 256 + threadIdx.x;
    if (m < M) {
        int pm = perm[m];
        fs[m] = make_int2(first[pm], second[pm]);
    }
}

// ---------------------------------------------------------------------------
// Message kernel (fp16 MFMA): wave = 16 messages in receiver-sorted order.
// msg = selu([h[f],h[s]] @ Wm + bm); segmented run-sum -> contiguous
// 256B atomic bursts into agg (f32). Weights register-resident (L1-hot).
// ---------------------------------------------------------------------------
__global__ __launch_bounds__(256) void msg_mfma(
    const _Float16* __restrict__ h16,
    const int2* __restrict__ fs,
    const half8* __restrict__ wB,   // [4nt][4kt][64] half8
    const float* __restrict__ bm,
    float* __restrict__ agg, int M)
{
    __shared__ float tile[4][16][64];
    __shared__ int skey[4][16];

    const int wid = threadIdx.x >> 6;
    const int lane = threadIdx.x & 63;
    const int t0 = (blockIdx.x * 4 + wid) * 16;

    half8 B[4][4];
    #pragma unroll
    for (int nt = 0; nt < 4; ++nt)
        #pragma unroll
        for (int kt = 0; kt < 4; ++kt)
            B[nt][kt] = wB[(nt * 4 + kt) * 64 + lane];

    int row = t0 + (lane & 15);
    bool rowv = (row < M);
    int2 p = fs[min(row, M - 1)];
    int fi = p.x, si = p.y;

    const half8* fr = reinterpret_cast<const half8*>(h16 + (size_t)fi * D);
    const half8* sr = reinterpret_cast<const half8*>(h16 + (size_t)si * D);
    const int hi = lane >> 4;
    half8 A[4];
    A[0] = fr[hi];
    A[1] = fr[4 + hi];
    A[2] = sr[hi];
    A[3] = sr[4 + hi];

    f32x4 acc[4];
    #pragma unroll
    for (int nt = 0; nt < 4; ++nt) acc[nt] = (f32x4){0.f, 0.f, 0.f, 0.f};

    #pragma unroll
    for (int nt = 0; nt < 4; ++nt)
        #pragma unroll
        for (int kt = 0; kt < 4; ++kt)
            acc[nt] = __builtin_amdgcn_mfma_f32_16x16x32_f16(A[kt], B[nt][kt], acc[nt], 0, 0, 0);

    #pragma unroll
    for (int nt = 0; nt < 4; ++nt) {
        int n = nt * 16 + (lane & 15);
        float bias = bm[n];
        #pragma unroll
        for (int r = 0; r < 4; ++r) {
            float v = acc[nt][r] + bias;
            v = (v > 0.0f) ? (SELU_SCALE * v)
                           : (SELU_SCALE * SELU_ALPHA) * (__expf(v) - 1.0f);
            tile[wid][hi * 4 + r][n] = v;
        }
    }
    if (lane < 16) skey[wid][lane] = rowv ? si : -1;
    __syncthreads();

    float run = 0.0f;
    int kprev = skey[wid][0];
    #pragma unroll
    for (int m = 0; m < 16; ++m) {
        int km = skey[wid][m];
        if (km != kprev) {
            if (kprev >= 0) unsafeAtomicAdd(agg + (size_t)kprev * D + lane, run);
            run = 0.0f;
            kprev = km;
        }
        run += tile[wid][m][lane];
    }
    if (kprev >= 0) unsafeAtomicAdd(agg + (size_t)kprev * D + lane, run);
}

// ---------------------------------------------------------------------------
// Update GRU (fp16 MFMA): wave = 32 edges (2 groups of 16). NO LDS: B-frags
// read directly from global (L2-hot, shared by all blocks) -> occupancy
// VGPR-limited (~4-5 waves/SIMD) instead of LDS-limited (2).
// ---------------------------------------------------------------------------
__global__ __launch_bounds__(256) void upd_mfma(
    float* __restrict__ agg,
    float* __restrict__ h32,
    _Float16* __restrict__ h16,
    const half8* __restrict__ wWu,  // [12nt][2kt][64]
    const half8* __restrict__ wUu,  // [12nt][2kt][64]
    const float* __restrict__ bu,
    int E)
{
    const int wid = threadIdx.x >> 6;
    const int lane = threadIdx.x & 63;
    const int hi = lane >> 4;
    const int e0 = (blockIdx.x * 4 + wid) * 32;

    half8 AX[2][2], AH[2][2];
    #pragma unroll
    for (int g = 0; g < 2; ++g) {
        int ec = min(e0 + g * 16 + (lane & 15), E - 1);
        #pragma unroll
        for (int kt = 0; kt < 2; ++kt) {
            const float* ap = agg + (size_t)ec * D + 32 * kt + 8 * hi;
            float4 x0 = *reinterpret_cast<const float4*>(ap);
            float4 x1 = *reinterpret_cast<const float4*>(ap + 4);
            half8 ax;
            ax[0] = (_Float16)x0.x; ax[1] = (_Float16)x0.y;
            ax[2] = (_Float16)x0.z; ax[3] = (_Float16)x0.w;
            ax[4] = (_Float16)x1.x; ax[5] = (_Float16)x1.y;
            ax[6] = (_Float16)x1.z; ax[7] = (_Float16)x1.w;
            AX[g][kt] = ax;
            AH[g][kt] = reinterpret_cast<const half8*>(h16 + (size_t)ec * D)[4 * kt + hi];
        }
    }

    #pragma unroll 1
    for (int i = 0; i < 4; ++i) {
        half8 WBz[2], WBr[2], WBc[2], UBz[2], UBr[2], UBc[2];
        #pragma unroll
        for (int kt = 0; kt < 2; ++kt) {
            WBz[kt] = wWu[((0 + i) * 2 + kt) * 64 + lane];
            WBr[kt] = wWu[((4 + i) * 2 + kt) * 64 + lane];
            WBc[kt] = wWu[((8 + i) * 2 + kt) * 64 + lane];
            UBz[kt] = wUu[((0 + i) * 2 + kt) * 64 + lane];
            UBr[kt] = wUu[((4 + i) * 2 + kt) * 64 + lane];
            UBc[kt] = wUu[((8 + i) * 2 + kt) * 64 + lane];
        }
        int n = 16 * i + (lane & 15);
        float bz  = bu[n] + bu[192 + n];
        float brr = bu[64 + n] + bu[256 + n];
        float bx  = bu[128 + n];
        float bh  = bu[320 + n];

        #pragma unroll
        for (int g = 0; g < 2; ++g) {
            f32x4 az  = (f32x4){0.f, 0.f, 0.f, 0.f};
            f32x4 ar_ = (f32x4){0.f, 0.f, 0.f, 0.f};
            f32x4 acx = (f32x4){0.f, 0.f, 0.f, 0.f};
            f32x4 ach = (f32x4){0.f, 0.f, 0.f, 0.f};
            #pragma unroll
            for (int kt = 0; kt < 2; ++kt) {
                az  = __builtin_amdgcn_mfma_f32_16x16x32_f16(AX[g][kt], WBz[kt], az, 0, 0, 0);
                az  = __builtin_amdgcn_mfma_f32_16x16x32_f16(AH[g][kt], UBz[kt], az, 0, 0, 0);
                ar_ = __builtin_amdgcn_mfma_f32_16x16x32_f16(AX[g][kt], WBr[kt], ar_, 0, 0, 0);
                ar_ = __builtin_amdgcn_mfma_f32_16x16x32_f16(AH[g][kt], UBr[kt], ar_, 0, 0, 0);
                acx = __builtin_amdgcn_mfma_f32_16x16x32_f16(AX[g][kt], WBc[kt], acx, 0, 0, 0);
                ach = __builtin_amdgcn_mfma_f32_16x16x32_f16(AH[g][kt], UBc[kt], ach, 0, 0, 0);
            }
            #pragma unroll
            for (int r = 0; r < 4; ++r) {
                int e = e0 + g * 16 + hi * 4 + r;
                if (e < E) {
                    float z = fast_sig(az[r] + bz);
                    float rr = fast_sig(ar_[r] + brr);
                    float c = fast_tanh(acx[r] + bx + rr * (ach[r] + bh));
                    float hp = h32[(size_t)e * D + n];
                    float hn = z * hp + (1.0f - z) * c;
                    h32[(size_t)e * D + n] = hn;
                    h16[(size_t)e * D + n] = (_Float16)hn;
                    agg[(size_t)e * D + n] = 0.0f;
                }
            }
        }
    }
}

// ---------------------------------------------------------------------------
// Readout GRU (fp16 MFMA): wave = 32 edges (2 groups), blockIdx.y = col half.
// NO LDS: B-frags direct from global (L2-hot) -> 4-5 waves/SIMD occupancy.
// ---------------------------------------------------------------------------
__global__ __launch_bounds__(256) void ro_mfma(
    const _Float16* __restrict__ h16,
    const _Float16* __restrict__ hin,
    _Float16* __restrict__ hout,
    const half8* __restrict__ wWr,  // [24nt][2kt][64]
    const half8* __restrict__ wUr,  // [24nt][4kt][64]
    const float* __restrict__ br,
    int E)
{
    const int ch = blockIdx.y;
    const int wid = threadIdx.x >> 6;
    const int lane = threadIdx.x & 63;
    const int hi = lane >> 4;
    const int e0 = (blockIdx.x * 4 + wid) * 32;

    half8 AX[2][2], AH[2][4];
    #pragma unroll
    for (int g = 0; g < 2; ++g) {
        int ec = min(e0 + g * 16 + (lane & 15), E - 1);
        #pragma unroll
        for (int kt = 0; kt < 2; ++kt)
            AX[g][kt] = reinterpret_cast<const half8*>(h16 + (size_t)ec * D)[4 * kt + hi];
        #pragma unroll
        for (int kt = 0; kt < 4; ++kt)
            AH[g][kt] = reinterpret_cast<const half8*>(hin + (size_t)ec * R)[4 * kt + hi];
    }

    #pragma unroll 1
    for (int i = 0; i < 4; ++i) {
        // gate g: W ntg = 8*g + 4*ch + i ; U ntg = 8*g + 4*ch + i
        half8 WBz[2], WBr[2], WBx[2], UBz[4], UBr[4], UBh[4];
        #pragma unroll
        for (int kt = 0; kt < 2; ++kt) {
            WBz[kt] = wWr[((4 * ch + i) * 2 + kt) * 64 + lane];
            WBr[kt] = wWr[((8 + 4 * ch + i) * 2 + kt) * 64 + lane];
            WBx[kt] = wWr[((16 + 4 * ch + i) * 2 + kt) * 64 + lane];
        }
        #pragma unroll
        for (int kt = 0; kt < 4; ++kt) {
            UBz[kt] = wUr[((4 * ch + i) * 4 + kt) * 64 + lane];
            UBr[kt] = wUr[((8 + 4 * ch + i) * 4 + kt) * 64 + lane];
            UBh[kt] = wUr[((16 + 4 * ch + i) * 4 + kt) * 64 + lane];
        }
        int c = 64 * ch + 16 * i + (lane & 15);
        float bz  = br[c] + br[384 + c];
        float brr = br[128 + c] + br[512 + c];
        float bx  = br[256 + c];
        float bh  = br[640 + c];

        #pragma unroll
        for (int g = 0; g < 2; ++g) {
            f32x4 az  = (f32x4){0.f, 0.f, 0.f, 0.f};
            f32x4 ar_ = (f32x4){0.f, 0.f, 0.f, 0.f};
            f32x4 acx = (f32x4){0.f, 0.f, 0.f, 0.f};
            f32x4 ach = (f32x4){0.f, 0.f, 0.f, 0.f};
            #pragma unroll
            for (int kt = 0; kt < 2; ++kt) {
                az  = __builtin_amdgcn_mfma_f32_16x16x32_f16(AX[g][kt], WBz[kt], az, 0, 0, 0);
                ar_ = __builtin_amdgcn_mfma_f32_16x16x32_f16(AX[g][kt], WBr[kt], ar_, 0, 0, 0);
                acx = __builtin_amdgcn_mfma_f32_16x16x32_f16(AX[g][kt], WBx[kt], acx, 0, 0, 0);
            }
            #pragma unroll
            for (int kt = 0; kt < 4; ++kt) {
                az  = __builtin_amdgcn_mfma_f32_16x16x32_f16(AH[g][kt], UBz[kt], az, 0, 0, 0);
                ar_ = __builtin_amdgcn_mfma_f32_16x16x32_f16(AH[g][kt], UBr[kt], ar_, 0, 0, 0);
                ach = __builtin_amdgcn_mfma_f32_16x16x32_f16(AH[g][kt], UBh[kt], ach, 0, 0, 0);
            }
            #pragma unroll
            for (int r = 0; r < 4; ++r) {
                int e = e0 + g * 16 + hi * 4 + r;
                if (e < E) {
                    float z = fast_sig(az[r] + bz);
                    float rr = fast_sig(ar_[r] + brr);
                    float cc = fast_tanh(acx[r] + bx + rr * (ach[r] + bh));
                    float hp = (float)hin[(size_t)e * R + c];
                    hout[(size_t)e * R + c] = (_Float16)(z * hp + (1.0f - z) * cc);
                }
            }
        }
    }
}

// ---------------------------------------------------------------------------
// Output: out[g] = b_out + sum_{e: gid[e]==g} dot(hro[e], W_out)
// gids sorted -> wave-level segmented scan; sentinel g=-1 for OOB lanes.
// ---------------------------------------------------------------------------
__global__ void out_init_kernel(float* __restrict__ out, const float* __restrict__ b_out, int G) {
    int g = blockIdx.x * blockDim.x + threadIdx.x;
    if (g < G) out[g] = b_out[0];
}

__global__ __launch_bounds__(256) void out_kernel(
    const _Float16* __restrict__ hro,
    const int* __restrict__ gid,
    const float* __restrict__ Wout,
    float* __restrict__ out,
    int E)
{
    int e = blockIdx.x * 256 + threadIdx.x;
    int lane = threadIdx.x & 63;
    int ec = min(e, E - 1);
    const half8* hp = reinterpret_cast<const half8*>(hro + (size_t)ec * R);
    float s = 0.0f;
    #pragma unroll
    for (int kk = 0; kk < R / 8; ++kk) {
        half8 v = hp[kk];
        #pragma unroll
        for (int j = 0; j < 8; ++j)
            s = fmaf((float)v[j], Wout[kk * 8 + j], s);
    }
    bool valid = (e < E);
    if (!valid) s = 0.0f;
    int g = valid ? gid[ec] : -1;
    #pragma unroll
    for (int d = 1; d < 64; d <<= 1) {
        float t = __shfl_up(s, d);
        int kg = __shfl_up(g, d);
        if (lane >= d && kg == g) s += t;
    }
    int gnext = __shfl_down(g, 1);
    bool tail = (lane == 63) || (gnext != g);
    if (tail && valid) unsafeAtomicAdd(out + g, s);
}

// ---------------------------------------------------------------------------
extern "C" void kernel_launch(void* const* d_in, const int* in_sizes, int n_in,
                              void* d_out, int out_size, void* d_ws, size_t ws_size,
                              hipStream_t stream) {
    const float* link_state = (const float*)d_in[0];
    const int*   first      = (const int*)d_in[1];
    const int*   second     = (const int*)d_in[2];
    const int*   gids       = (const int*)d_in[3];
    const float* Wm         = (const float*)d_in[5];
    const float* bm         = (const float*)d_in[6];
    const float* Wu         = (const float*)d_in[7];
    const float* Uu         = (const float*)d_in[8];
    const float* bu         = (const float*)d_in[9];
    const float* Wr         = (const float*)d_in[10];
    const float* Ur         = (const float*)d_in[11];
    const float* brb        = (const float*)d_in[12];
    const float* Wout       = (const float*)d_in[13];
    const float* bout       = (const float*)d_in[14];

    const int E = in_sizes[0] / D;
    const int M = in_sizes[1];
    const int G = out_size;

    char* p = (char*)d_ws;
    auto carve = [&](size_t bytes) {
        void* r = (void*)p;
        p += (bytes + 255) & ~(size_t)255;
        return r;
    };
    float*     h32  = (float*)carve((size_t)E * D * 4);
    _Float16*  h16  = (_Float16*)carve((size_t)E * D * 2);
    float*     agg  = (float*)carve((size_t)E * D * 4);
    _Float16*  hroA = (_Float16*)carve((size_t)E * R * 2);
    _Float16*  hroB = (_Float16*)carve((size_t)E * R * 2);
    int*       perm = (int*)carve((size_t)M * 4);
    int2*      fs   = (int2*)carve((size_t)M * 8);
    int*       cnt  = (int*)carve((size_t)E * 4);
    int*       cur  = (int*)carve((size_t)E * 4);
    int*       off  = (int*)carve((size_t)(E + 1) * 4);
    int*       bsum = (int*)carve(4096 * 4);
    _Float16*  wWm  = (_Float16*)carve(8192 * 2);
    _Float16*  wWu  = (_Float16*)carve(12288 * 2);
    _Float16*  wUu  = (_Float16*)carve(12288 * 2);
    _Float16*  wWr  = (_Float16*)carve(24576 * 2);
    _Float16*  wUr  = (_Float16*)carve(49152 * 2);

    hipMemcpyAsync(h32, link_state, (size_t)E * D * 4, hipMemcpyDeviceToDevice, stream);
    hipMemsetAsync(agg, 0, (size_t)E * D * 4, stream);
    hipMemsetAsync(hroA, 0, (size_t)E * R * 2, stream);
    hipMemsetAsync(cnt, 0, (size_t)E * 4, stream);
    hipMemsetAsync(cur, 0, (size_t)E * 4, stream);

    h16_init<<<(E * D + 255) / 256, 256, 0, stream>>>(link_state, h16, E * D);
    swizzle_all<<<dim3(192, 5), 256, 0, stream>>>(Wm, Wu, Uu, Wr, Ur,
                                                  wWm, wWu, wUu, wWr, wUr);

    const int NB = (E + 255) / 256;   // 391 for E=100k; scan_part handles <=1024
    hist_kernel<<<(M + 255) / 256, 256, 0, stream>>>(second, cnt, M);
    scan_bsum<<<NB, 256, 0, stream>>>(cnt, bsum, E);
    scan_part<<<1, 1024, 0, stream>>>(bsum, NB);
    scan_final<<<NB, 256, 0, stream>>>(cnt, bsum, off, E);
    scatter_kernel<<<(M + 255) / 256, 256, 0, stream>>>(second, off, cur, perm, M);
    fs_pack<<<(M + 255) / 256, 256, 0, stream>>>(first, second, perm, fs, M);

    const int msg_blocks = (M + 63) / 64;
    const int e_blocks = (E + 127) / 128;

    _Float16* rin = hroA;
    _Float16* rout = hroB;
    for (int t = 0; t < NSTEPS; ++t) {
        msg_mfma<<<msg_blocks, 256, 0, stream>>>(h16, fs, (const half8*)wWm, bm, agg, M);
        upd_mfma<<<e_blocks, 256, 0, stream>>>(agg, h32, h16,
                                               (const half8*)wWu, (const half8*)wUu, bu, E);
        ro_mfma<<<dim3(e_blocks, 2), 256, 0, stream>>>(h16, rin, rout,
                                                       (const half8*)wWr, (const half8*)wUr, brb, E);
        _Float16* tmp = rin; rin = rout; rout = tmp;
    }

    out_init_kernel<<<(G + 255) / 256, 256, 0, stream>>>((float*)d_out, bout, G);
    out_kernel<<<(E + 255) / 256, 256, 0, stream>>>(rin, gids, Wout, (float*)d_out, E);
}

// Round 6
// 1138.301 us; speedup vs baseline: 18.7402x; 1.0444x over previous
//
#include <hip/hip_runtime.h>
#include <hip/hip_bf16.h>

#define D 64
#define R 128
#define NSTEPS 8
#define SELU_SCALE 1.0507009873554805f
#define SELU_ALPHA 1.6732632423543772f

typedef _Float16 half8 __attribute__((ext_vector_type(8)));
typedef float f32x4 __attribute__((ext_vector_type(4)));

__device__ __forceinline__ float fast_sig(float x) {
    return __fdividef(1.0f, 1.0f + __expf(-x));
}
__device__ __forceinline__ float fast_tanh(float x) {
    float xc = fminf(fmaxf(x, -15.0f), 15.0f);
    float e = __expf(2.0f * xc);
    return 1.0f - __fdividef(2.0f, e + 1.0f);
}

// ---------------------------------------------------------------------------
// Prep: all 5 weight swizzles in ONE kernel. fp32 [K][N] -> fp16 MFMA
// B-fragment order: dst[((nt*KT+kt)*64+lane)*8+j] =
//   src[(32*kt + 8*(lane>>4) + j)*N + 16*nt + (lane&15)]
// ---------------------------------------------------------------------------
__global__ __launch_bounds__(256) void swizzle_all(
    const float* __restrict__ Wm, const float* __restrict__ Wu,
    const float* __restrict__ Uu, const float* __restrict__ Wr,
    const float* __restrict__ Ur,
    _Float16* __restrict__ wWm, _Float16* __restrict__ wWu,
    _Float16* __restrict__ wUu, _Float16* __restrict__ wWr,
    _Float16* __restrict__ wUr)
{
    const float* src; _Float16* dst; int K, N;
    switch (blockIdx.y) {
        case 0: src = Wm; dst = wWm; K = 128; N = 64;  break;
        case 1: src = Wu; dst = wWu; K = 64;  N = 192; break;
        case 2: src = Uu; dst = wUu; K = 64;  N = 192; break;
        case 3: src = Wr; dst = wWr; K = 64;  N = 384; break;
        default: src = Ur; dst = wUr; K = 128; N = 384; break;
    }
    int idx = blockIdx.x * 256 + threadIdx.x;
    int KT = K >> 5;
    int total = KT * (N >> 4) * 512;
    if (idx >= total) return;
    int j = idx & 7;
    int lane = (idx >> 3) & 63;
    int kt = (idx >> 9) % KT;
    int nt = idx / (512 * KT);
    int k = 32 * kt + 8 * (lane >> 4) + j;
    int n = 16 * nt + (lane & 15);
    dst[idx] = (_Float16)src[(size_t)k * N + n];
}

__global__ __launch_bounds__(256) void h16_init(const float* __restrict__ src,
                                                _Float16* __restrict__ dst, int n) {
    int i = blockIdx.x * 256 + threadIdx.x;
    if (i < n) dst[i] = (_Float16)src[i];
}

// ---------------------------------------------------------------------------
// CSR build: hist -> 3-kernel scan -> scatter -> fs pack
// ---------------------------------------------------------------------------
__global__ __launch_bounds__(256) void hist_kernel(const int* __restrict__ second,
                                                   int* __restrict__ cnt, int M) {
    int m = blockIdx.x * 256 + threadIdx.x;
    if (m < M) atomicAdd(&cnt[second[m]], 1);
}

__global__ __launch_bounds__(256) void scan_bsum(const int* __restrict__ cnt,
                                                 int* __restrict__ bsum, int E) {
    int i = blockIdx.x * 256 + threadIdx.x;
    int tid = threadIdx.x;
    int v = (i < E) ? cnt[i] : 0;
    __shared__ int s[256];
    s[tid] = v;
    __syncthreads();
    #pragma unroll
    for (int d = 1; d < 256; d <<= 1) {
        int t = (tid >= d) ? s[tid - d] : 0;
        __syncthreads();
        s[tid] += t;
        __syncthreads();
    }
    if (tid == 255) bsum[blockIdx.x] = s[255];
}

__global__ __launch_bounds__(1024) void scan_part(int* __restrict__ bsum, int NB) {
    int tid = threadIdx.x;
    __shared__ int s[1024];
    int v = (tid < NB) ? bsum[tid] : 0;
    s[tid] = v;
    __syncthreads();
    #pragma unroll
    for (int d = 1; d < 1024; d <<= 1) {
        int t = (tid >= d) ? s[tid - d] : 0;
        __syncthreads();
        s[tid] += t;
        __syncthreads();
    }
    if (tid < NB) bsum[tid] = s[tid] - v;   // exclusive
}

__global__ __launch_bounds__(256) void scan_final(const int* __restrict__ cnt,
                                                  const int* __restrict__ bsum,
                                                  int* __restrict__ off, int E) {
    int i = blockIdx.x * 256 + threadIdx.x;
    int tid = threadIdx.x;
    int v = (i < E) ? cnt[i] : 0;
    __shared__ int s[256];
    s[tid] = v;
    __syncthreads();
    #pragma unroll
    for (int d = 1; d < 256; d <<= 1) {
        int t = (tid >= d) ? s[tid - d] : 0;
        __syncthreads();
        s[tid] += t;
        __syncthreads();
    }
    if (i < E) off[i] = bsum[blockIdx.x] + s[tid] - v;
}

__global__ __launch_bounds__(256) void scatter_kernel(const int* __restrict__ second,
                                                      const int* __restrict__ off,
                                                      int* __restrict__ cur,
                                                      int* __restrict__ perm, int M) {
    int m = blockIdx.x * 256 + threadIdx.x;
    if (m < M) {
        int s = second[m];
        int p = atomicAdd(&cur[s], 1);
        perm[off[s] + p] = m;
    }
}

__global__ __launch_bounds__(256) void fs_pack(const int* __restrict__ first,
                                               const int* __restrict__ second,
                                               const int* __restrict__ perm,
                                               int2* __restrict__ fs, int M) {
    int m = blockIdx.x * 256 + threadIdx.x;
    if (m < M) {
        int pm = perm[m];
        fs[m] = make_int2(first[pm], second[pm]);
    }
}

// ---------------------------------------------------------------------------
// Message kernel (fp16 MFMA): wave = 16 messages in receiver-sorted order.
// msg = selu([h[f],h[s]] @ Wm + bm); segmented run-sum -> contiguous
// 256B atomic bursts into agg (f32). Weights register-resident.
// ---------------------------------------------------------------------------
__global__ __launch_bounds__(256) void msg_mfma(
    const _Float16* __restrict__ h16,
    const int2* __restrict__ fs,
    const half8* __restrict__ wB,   // [4nt][4kt][64] half8
    const float* __restrict__ bm,
    float* __restrict__ agg, int M)
{
    __shared__ float tile[4][16][64];
    __shared__ int skey[4][16];

    const int wid = threadIdx.x >> 6;
    const int lane = threadIdx.x & 63;
    const int t0 = (blockIdx.x * 4 + wid) * 16;

    half8 B[4][4];
    #pragma unroll
    for (int nt = 0; nt < 4; ++nt)
        #pragma unroll
        for (int kt = 0; kt < 4; ++kt)
            B[nt][kt] = wB[(nt * 4 + kt) * 64 + lane];

    int row = t0 + (lane & 15);
    bool rowv = (row < M);
    int2 p = fs[min(row, M - 1)];
    int fi = p.x, si = p.y;

    const half8* fr = reinterpret_cast<const half8*>(h16 + (size_t)fi * D);
    const half8* sr = reinterpret_cast<const half8*>(h16 + (size_t)si * D);
    const int hi = lane >> 4;
    half8 A[4];
    A[0] = fr[hi];
    A[1] = fr[4 + hi];
    A[2] = sr[hi];
    A[3] = sr[4 + hi];

    f32x4 acc[4];
    #pragma unroll
    for (int nt = 0; nt < 4; ++nt) acc[nt] = (f32x4){0.f, 0.f, 0.f, 0.f};

    #pragma unroll
    for (int nt = 0; nt < 4; ++nt)
        #pragma unroll
        for (int kt = 0; kt < 4; ++kt)
            acc[nt] = __builtin_amdgcn_mfma_f32_16x16x32_f16(A[kt], B[nt][kt], acc[nt], 0, 0, 0);

    #pragma unroll
    for (int nt = 0; nt < 4; ++nt) {
        int n = nt * 16 + (lane & 15);
        float bias = bm[n];
        #pragma unroll
        for (int r = 0; r < 4; ++r) {
            float v = acc[nt][r] + bias;
            v = (v > 0.0f) ? (SELU_SCALE * v)
                           : (SELU_SCALE * SELU_ALPHA) * (__expf(v) - 1.0f);
            tile[wid][hi * 4 + r][n] = v;
        }
    }
    if (lane < 16) skey[wid][lane] = rowv ? si : -1;
    __syncthreads();

    float run = 0.0f;
    int kprev = skey[wid][0];
    #pragma unroll
    for (int m = 0; m < 16; ++m) {
        int km = skey[wid][m];
        if (km != kprev) {
            if (kprev >= 0) unsafeAtomicAdd(agg + (size_t)kprev * D + lane, run);
            run = 0.0f;
            kprev = km;
        }
        run += tile[wid][m][lane];
    }
    if (kprev >= 0) unsafeAtomicAdd(agg + (size_t)kprev * D + lane, run);
}

// ---------------------------------------------------------------------------
// Fused update-GRU + readout-GRU. Wave = 32 edges (2 groups of 16).
//  phase 1: h' = GRU_upd(agg[e], h16[e])  (fp16 h carry, no h32)
//           writes h16', zeroes agg
//  phase 2: hro[e] = GRU_ro(h', hro[e])   in-place, all 128 cols
// h' re-read as A-fragments from h16 (same wave just wrote it -> L1 hot).
// hro fragments prefetched at kernel start (latency hidden under phase 1).
// ---------------------------------------------------------------------------
__global__ __launch_bounds__(256) void fused_ur(
    float* __restrict__ agg,
    _Float16* h16,                  // written then re-read (same pointer)
    _Float16* hro,                  // in-place state
    const half8* __restrict__ wWu,  // [12nt][2kt][64]
    const half8* __restrict__ wUu,  // [12nt][2kt][64]
    const float* __restrict__ bu,
    const half8* __restrict__ wWr,  // [24nt][2kt][64]
    const half8* __restrict__ wUr,  // [24nt][4kt][64]
    const float* __restrict__ br,
    int E)
{
    const int wid = threadIdx.x >> 6;
    const int lane = threadIdx.x & 63;
    const int hi = lane >> 4;
    const int e0 = (blockIdx.x * 4 + wid) * 32;

    int ec[2];
    ec[0] = min(e0 + (lane & 15), E - 1);
    ec[1] = min(e0 + 16 + (lane & 15), E - 1);

    // early prefetch: readout state fragments (consumed in phase 2)
    half8 AHro[2][4];
    #pragma unroll
    for (int g = 0; g < 2; ++g)
        #pragma unroll
        for (int kt = 0; kt < 4; ++kt)
            AHro[g][kt] = reinterpret_cast<const half8*>(hro + (size_t)ec[g] * R)[4 * kt + hi];

    // update-GRU inputs
    half8 AX[2][2], AHu[2][2];
    #pragma unroll
    for (int g = 0; g < 2; ++g) {
        #pragma unroll
        for (int kt = 0; kt < 2; ++kt) {
            const float* ap = agg + (size_t)ec[g] * D + 32 * kt + 8 * hi;
            float4 x0 = *reinterpret_cast<const float4*>(ap);
            float4 x1 = *reinterpret_cast<const float4*>(ap + 4);
            half8 ax;
            ax[0] = (_Float16)x0.x; ax[1] = (_Float16)x0.y;
            ax[2] = (_Float16)x0.z; ax[3] = (_Float16)x0.w;
            ax[4] = (_Float16)x1.x; ax[5] = (_Float16)x1.y;
            ax[6] = (_Float16)x1.z; ax[7] = (_Float16)x1.w;
            AX[g][kt] = ax;
            AHu[g][kt] = reinterpret_cast<const half8*>(h16 + (size_t)ec[g] * D)[4 * kt + hi];
        }
    }

    // ---- phase 1: update GRU ----
    #pragma unroll 1
    for (int i = 0; i < 4; ++i) {
        half8 WBz[2], WBr[2], WBc[2], UBz[2], UBr[2], UBc[2];
        #pragma unroll
        for (int kt = 0; kt < 2; ++kt) {
            WBz[kt] = wWu[((0 + i) * 2 + kt) * 64 + lane];
            WBr[kt] = wWu[((4 + i) * 2 + kt) * 64 + lane];
            WBc[kt] = wWu[((8 + i) * 2 + kt) * 64 + lane];
            UBz[kt] = wUu[((0 + i) * 2 + kt) * 64 + lane];
            UBr[kt] = wUu[((4 + i) * 2 + kt) * 64 + lane];
            UBc[kt] = wUu[((8 + i) * 2 + kt) * 64 + lane];
        }
        int n = 16 * i + (lane & 15);
        float bz  = bu[n] + bu[192 + n];
        float brr = bu[64 + n] + bu[256 + n];
        float bx  = bu[128 + n];
        float bh  = bu[320 + n];

        #pragma unroll
        for (int g = 0; g < 2; ++g) {
            f32x4 az  = (f32x4){0.f, 0.f, 0.f, 0.f};
            f32x4 ar_ = (f32x4){0.f, 0.f, 0.f, 0.f};
            f32x4 acx = (f32x4){0.f, 0.f, 0.f, 0.f};
            f32x4 ach = (f32x4){0.f, 0.f, 0.f, 0.f};
            #pragma unroll
            for (int kt = 0; kt < 2; ++kt) {
                az  = __builtin_amdgcn_mfma_f32_16x16x32_f16(AX[g][kt], WBz[kt], az, 0, 0, 0);
                az  = __builtin_amdgcn_mfma_f32_16x16x32_f16(AHu[g][kt], UBz[kt], az, 0, 0, 0);
                ar_ = __builtin_amdgcn_mfma_f32_16x16x32_f16(AX[g][kt], WBr[kt], ar_, 0, 0, 0);
                ar_ = __builtin_amdgcn_mfma_f32_16x16x32_f16(AHu[g][kt], UBr[kt], ar_, 0, 0, 0);
                acx = __builtin_amdgcn_mfma_f32_16x16x32_f16(AX[g][kt], WBc[kt], acx, 0, 0, 0);
                ach = __builtin_amdgcn_mfma_f32_16x16x32_f16(AHu[g][kt], UBc[kt], ach, 0, 0, 0);
            }
            #pragma unroll
            for (int r = 0; r < 4; ++r) {
                int e = e0 + g * 16 + hi * 4 + r;
                if (e < E) {
                    float z = fast_sig(az[r] + bz);
                    float rr = fast_sig(ar_[r] + brr);
                    float c = fast_tanh(acx[r] + bx + rr * (ach[r] + bh));
                    float hp = (float)h16[(size_t)e * D + n];   // old h (fp16 carry)
                    float hn = z * hp + (1.0f - z) * c;
                    h16[(size_t)e * D + n] = (_Float16)hn;
                    agg[(size_t)e * D + n] = 0.0f;
                }
            }
        }
    }

    __threadfence_block();   // drain h16 stores before fragment re-read

    half8 AXn[2][2];
    #pragma unroll
    for (int g = 0; g < 2; ++g)
        #pragma unroll
        for (int kt = 0; kt < 2; ++kt)
            AXn[g][kt] = reinterpret_cast<const half8*>(h16 + (size_t)ec[g] * D)[4 * kt + hi];

    // ---- phase 2: readout GRU, all 128 columns ----
    #pragma unroll 1
    for (int it = 0; it < 8; ++it) {
        half8 WBz[2], WBr[2], WBx[2], UBz[4], UBr[4], UBh[4];
        #pragma unroll
        for (int kt = 0; kt < 2; ++kt) {
            WBz[kt] = wWr[((0 + it) * 2 + kt) * 64 + lane];
            WBr[kt] = wWr[((8 + it) * 2 + kt) * 64 + lane];
            WBx[kt] = wWr[((16 + it) * 2 + kt) * 64 + lane];
        }
        #pragma unroll
        for (int kt = 0; kt < 4; ++kt) {
            UBz[kt] = wUr[((0 + it) * 4 + kt) * 64 + lane];
            UBr[kt] = wUr[((8 + it) * 4 + kt) * 64 + lane];
            UBh[kt] = wUr[((16 + it) * 4 + kt) * 64 + lane];
        }
        int c = it * 16 + (lane & 15);
        float bz  = br[c] + br[384 + c];
        float brr = br[128 + c] + br[512 + c];
        float bx  = br[256 + c];
        float bh  = br[640 + c];

        #pragma unroll
        for (int g = 0; g < 2; ++g) {
            f32x4 az  = (f32x4){0.f, 0.f, 0.f, 0.f};
            f32x4 ar_ = (f32x4){0.f, 0.f, 0.f, 0.f};
            f32x4 acx = (f32x4){0.f, 0.f, 0.f, 0.f};
            f32x4 ach = (f32x4){0.f, 0.f, 0.f, 0.f};
            #pragma unroll
            for (int kt = 0; kt < 2; ++kt) {
                az  = __builtin_amdgcn_mfma_f32_16x16x32_f16(AXn[g][kt], WBz[kt], az, 0, 0, 0);
                ar_ = __builtin_amdgcn_mfma_f32_16x16x32_f16(AXn[g][kt], WBr[kt], ar_, 0, 0, 0);
                acx = __builtin_amdgcn_mfma_f32_16x16x32_f16(AXn[g][kt], WBx[kt], acx, 0, 0, 0);
            }
            #pragma unroll
            for (int kt = 0; kt < 4; ++kt) {
                az  = __builtin_amdgcn_mfma_f32_16x16x32_f16(AHro[g][kt], UBz[kt], az, 0, 0, 0);
                ar_ = __builtin_amdgcn_mfma_f32_16x16x32_f16(AHro[g][kt], UBr[kt], ar_, 0, 0, 0);
                ach = __builtin_amdgcn_mfma_f32_16x16x32_f16(AHro[g][kt], UBh[kt], ach, 0, 0, 0);
            }
            #pragma unroll
            for (int r = 0; r < 4; ++r) {
                int e = e0 + g * 16 + hi * 4 + r;
                if (e < E) {
                    float z = fast_sig(az[r] + bz);
                    float rr = fast_sig(ar_[r] + brr);
                    float cc = fast_tanh(acx[r] + bx + rr * (ach[r] + bh));
                    float hp = (float)hro[(size_t)e * R + c];
                    hro[(size_t)e * R + c] = (_Float16)(z * hp + (1.0f - z) * cc);
                }
            }
        }
    }
}

// ---------------------------------------------------------------------------
// Output: out[g] = b_out + sum_{e: gid[e]==g} dot(hro[e], W_out)
// gids sorted -> wave-level segmented scan; sentinel g=-1 for OOB lanes.
// ---------------------------------------------------------------------------
__global__ void out_init_kernel(float* __restrict__ out, const float* __restrict__ b_out, int G) {
    int g = blockIdx.x * blockDim.x + threadIdx.x;
    if (g < G) out[g] = b_out[0];
}

__global__ __launch_bounds__(256) void out_kernel(
    const _Float16* __restrict__ hro,
    const int* __restrict__ gid,
    const float* __restrict__ Wout,
    float* __restrict__ out,
    int E)
{
    int e = blockIdx.x * 256 + threadIdx.x;
    int lane = threadIdx.x & 63;
    int ec = min(e, E - 1);
    const half8* hp = reinterpret_cast<const half8*>(hro + (size_t)ec * R);
    float s = 0.0f;
    #pragma unroll
    for (int kk = 0; kk < R / 8; ++kk) {
        half8 v = hp[kk];
        #pragma unroll
        for (int j = 0; j < 8; ++j)
            s = fmaf((float)v[j], Wout[kk * 8 + j], s);
    }
    bool valid = (e < E);
    if (!valid) s = 0.0f;
    int g = valid ? gid[ec] : -1;
    #pragma unroll
    for (int d = 1; d < 64; d <<= 1) {
        float t = __shfl_up(s, d);
        int kg = __shfl_up(g, d);
        if (lane >= d && kg == g) s += t;
    }
    int gnext = __shfl_down(g, 1);
    bool tail = (lane == 63) || (gnext != g);
    if (tail && valid) unsafeAtomicAdd(out + g, s);
}

// ---------------------------------------------------------------------------
extern "C" void kernel_launch(void* const* d_in, const int* in_sizes, int n_in,
                              void* d_out, int out_size, void* d_ws, size_t ws_size,
                              hipStream_t stream) {
    const float* link_state = (const float*)d_in[0];
    const int*   first      = (const int*)d_in[1];
    const int*   second     = (const int*)d_in[2];
    const int*   gids       = (const int*)d_in[3];
    const float* Wm         = (const float*)d_in[5];
    const float* bm         = (const float*)d_in[6];
    const float* Wu         = (const float*)d_in[7];
    const float* Uu         = (const float*)d_in[8];
    const float* bu         = (const float*)d_in[9];
    const float* Wr         = (const float*)d_in[10];
    const float* Ur         = (const float*)d_in[11];
    const float* brb        = (const float*)d_in[12];
    const float* Wout       = (const float*)d_in[13];
    const float* bout       = (const float*)d_in[14];

    const int E = in_sizes[0] / D;
    const int M = in_sizes[1];
    const int G = out_size;

    char* p = (char*)d_ws;
    auto carve = [&](size_t bytes) {
        void* r = (void*)p;
        p += (bytes + 255) & ~(size_t)255;
        return r;
    };
    _Float16*  h16  = (_Float16*)carve((size_t)E * D * 2);
    float*     agg  = (float*)carve((size_t)E * D * 4);
    _Float16*  hro  = (_Float16*)carve((size_t)E * R * 2);
    int*       perm = (int*)carve((size_t)M * 4);
    int2*      fs   = (int2*)carve((size_t)M * 8);
    int*       cnt  = (int*)carve((size_t)E * 4);
    int*       cur  = (int*)carve((size_t)E * 4);
    int*       off  = (int*)carve((size_t)(E + 1) * 4);
    int*       bsum = (int*)carve(4096 * 4);
    _Float16*  wWm  = (_Float16*)carve(8192 * 2);
    _Float16*  wWu  = (_Float16*)carve(12288 * 2);
    _Float16*  wUu  = (_Float16*)carve(12288 * 2);
    _Float16*  wWr  = (_Float16*)carve(24576 * 2);
    _Float16*  wUr  = (_Float16*)carve(49152 * 2);

    hipMemsetAsync(agg, 0, (size_t)E * D * 4, stream);
    hipMemsetAsync(hro, 0, (size_t)E * R * 2, stream);
    hipMemsetAsync(cnt, 0, (size_t)E * 4, stream);
    hipMemsetAsync(cur, 0, (size_t)E * 4, stream);

    h16_init<<<(E * D + 255) / 256, 256, 0, stream>>>(link_state, h16, E * D);
    swizzle_all<<<dim3(192, 5), 256, 0, stream>>>(Wm, Wu, Uu, Wr, Ur,
                                                  wWm, wWu, wUu, wWr, wUr);

    const int NB = (E + 255) / 256;   // 391 for E=100k; scan_part handles <=1024
    hist_kernel<<<(M + 255) / 256, 256, 0, stream>>>(second, cnt, M);
    scan_bsum<<<NB, 256, 0, stream>>>(cnt, bsum, E);
    scan_part<<<1, 1024, 0, stream>>>(bsum, NB);
    scan_final<<<NB, 256, 0, stream>>>(cnt, bsum, off, E);
    scatter_kernel<<<(M + 255) / 256, 256, 0, stream>>>(second, off, cur, perm, M);
    fs_pack<<<(M + 255) / 256, 256, 0, stream>>>(first, second, perm, fs, M);

    const int msg_blocks = (M + 63) / 64;
    const int e_blocks = (E + 127) / 128;

    for (int t = 0; t < NSTEPS; ++t) {
        msg_mfma<<<msg_blocks, 256, 0, stream>>>(h16, fs, (const half8*)wWm, bm, agg, M);
        fused_ur<<<e_blocks, 256, 0, stream>>>(agg, h16, hro,
                                               (const half8*)wWu, (const half8*)wUu, bu,
                                               (const half8*)wWr, (const half8*)wUr, brb, E);
    }

    out_init_kernel<<<(G + 255) / 256, 256, 0, stream>>>((float*)d_out, bout, G);
    out_kernel<<<(E + 255) / 256, 256, 0, stream>>>(hro, gids, Wout, (float*)d_out, E);
}

// Round 7
// 1081.790 us; speedup vs baseline: 19.7191x; 1.0522x over previous
//
#include <hip/hip_runtime.h>
#include <hip/hip_bf16.h>

#define D 64
#define R 128
#define NSTEPS 8
#define SELU_SCALE 1.0507009873554805f
#define SELU_ALPHA 1.6732632423543772f

typedef _Float16 half8 __attribute__((ext_vector_type(8)));
typedef float f32x4 __attribute__((ext_vector_type(4)));

__device__ __forceinline__ float fast_sig(float x) {
    return __fdividef(1.0f, 1.0f + __expf(-x));
}
__device__ __forceinline__ float fast_tanh(float x) {
    float xc = fminf(fmaxf(x, -15.0f), 15.0f);
    float e = __expf(2.0f * xc);
    return 1.0f - __fdividef(2.0f, e + 1.0f);
}

// ---------------------------------------------------------------------------
// Prep: all 5 weight swizzles in ONE kernel. fp32 [K][N] -> fp16 MFMA
// B-fragment order: dst[((nt*KT+kt)*64+lane)*8+j] =
//   src[(32*kt + 8*(lane>>4) + j)*N + 16*nt + (lane&15)]
// ---------------------------------------------------------------------------
__global__ __launch_bounds__(256) void swizzle_all(
    const float* __restrict__ Wm, const float* __restrict__ Wu,
    const float* __restrict__ Uu, const float* __restrict__ Wr,
    const float* __restrict__ Ur,
    _Float16* __restrict__ wWm, _Float16* __restrict__ wWu,
    _Float16* __restrict__ wUu, _Float16* __restrict__ wWr,
    _Float16* __restrict__ wUr)
{
    const float* src; _Float16* dst; int K, N;
    switch (blockIdx.y) {
        case 0: src = Wm; dst = wWm; K = 128; N = 64;  break;
        case 1: src = Wu; dst = wWu; K = 64;  N = 192; break;
        case 2: src = Uu; dst = wUu; K = 64;  N = 192; break;
        case 3: src = Wr; dst = wWr; K = 64;  N = 384; break;
        default: src = Ur; dst = wUr; K = 128; N = 384; break;
    }
    int idx = blockIdx.x * 256 + threadIdx.x;
    int KT = K >> 5;
    int total = KT * (N >> 4) * 512;
    if (idx >= total) return;
    int j = idx & 7;
    int lane = (idx >> 3) & 63;
    int kt = (idx >> 9) % KT;
    int nt = idx / (512 * KT);
    int k = 32 * kt + 8 * (lane >> 4) + j;
    int n = 16 * nt + (lane & 15);
    dst[idx] = (_Float16)src[(size_t)k * N + n];
}

__global__ __launch_bounds__(256) void h16_init(const float* __restrict__ src,
                                                _Float16* __restrict__ dst, int n) {
    int i = blockIdx.x * 256 + threadIdx.x;
    if (i < n) dst[i] = (_Float16)src[i];
}

// ---------------------------------------------------------------------------
// CSR build: hist -> 3-kernel scan -> scatter -> fs pack
// ---------------------------------------------------------------------------
__global__ __launch_bounds__(256) void hist_kernel(const int* __restrict__ second,
                                                   int* __restrict__ cnt, int M) {
    int m = blockIdx.x * 256 + threadIdx.x;
    if (m < M) atomicAdd(&cnt[second[m]], 1);
}

__global__ __launch_bounds__(256) void scan_bsum(const int* __restrict__ cnt,
                                                 int* __restrict__ bsum, int E) {
    int i = blockIdx.x * 256 + threadIdx.x;
    int tid = threadIdx.x;
    int v = (i < E) ? cnt[i] : 0;
    __shared__ int s[256];
    s[tid] = v;
    __syncthreads();
    #pragma unroll
    for (int d = 1; d < 256; d <<= 1) {
        int t = (tid >= d) ? s[tid - d] : 0;
        __syncthreads();
        s[tid] += t;
        __syncthreads();
    }
    if (tid == 255) bsum[blockIdx.x] = s[255];
}

__global__ __launch_bounds__(1024) void scan_part(int* __restrict__ bsum, int NB) {
    int tid = threadIdx.x;
    __shared__ int s[1024];
    int v = (tid < NB) ? bsum[tid] : 0;
    s[tid] = v;
    __syncthreads();
    #pragma unroll
    for (int d = 1; d < 1024; d <<= 1) {
        int t = (tid >= d) ? s[tid - d] : 0;
        __syncthreads();
        s[tid] += t;
        __syncthreads();
    }
    if (tid < NB) bsum[tid] = s[tid] - v;   // exclusive
}

__global__ __launch_bounds__(256) void scan_final(const int* __restrict__ cnt,
                                                  const int* __restrict__ bsum,
                                                  int* __restrict__ off, int E) {
    int i = blockIdx.x * 256 + threadIdx.x;
    int tid = threadIdx.x;
    int v = (i < E) ? cnt[i] : 0;
    __shared__ int s[256];
    s[tid] = v;
    __syncthreads();
    #pragma unroll
    for (int d = 1; d < 256; d <<= 1) {
        int t = (tid >= d) ? s[tid - d] : 0;
        __syncthreads();
        s[tid] += t;
        __syncthreads();
    }
    if (i < E) off[i] = bsum[blockIdx.x] + s[tid] - v;
}

__global__ __launch_bounds__(256) void scatter_kernel(const int* __restrict__ second,
                                                      const int* __restrict__ off,
                                                      int* __restrict__ cur,
                                                      int* __restrict__ perm, int M) {
    int m = blockIdx.x * 256 + threadIdx.x;
    if (m < M) {
        int s = second[m];
        int p = atomicAdd(&cur[s], 1);
        perm[off[s] + p] = m;
    }
}

__global__ __launch_bounds__(256) void fs_pack(const int* __restrict__ first,
                                               const int* __restrict__ second,
                                               const int* __restrict__ perm,
                                               int2* __restrict__ fs, int M) {
    int m = blockIdx.x * 256 + threadIdx.x;
    if (m < M) {
        int pm = perm[m];
        fs[m] = make_int2(first[pm], second[pm]);
    }
}

// ---------------------------------------------------------------------------
// Mega-step kernel: msg + update-GRU + readout-GRU, one launch per MP step.
// Wave owns 32 edges (2 groups of 16). Per group:
//  - messages [off[a], off_end) are CSR-contiguous; compute in 16-msg MFMA
//    chunks, selu -> LDS stage tile, segmented run-sum -> LDS agg tile.
//  - agg tile -> AX fragments; update GRU; h' -> hout + staged in agg tile.
//  - readout GRU (all 128 cols) in-place on hro.
// All tiles per-wave (padded rows, 65 f32) -> no __syncthreads anywhere.
// hin/hout ping-pong across steps keeps message gathers race-free.
// ---------------------------------------------------------------------------
__global__ __launch_bounds__(256) void step_fused(
    const _Float16* __restrict__ hin,
    _Float16* __restrict__ hout,
    _Float16* hro,
    const int2* __restrict__ fs,
    const int* __restrict__ off,
    const half8* __restrict__ wBm,  // [4nt][4kt][64]
    const float* __restrict__ bm,
    const half8* __restrict__ wWu,  // [12nt][2kt][64]
    const half8* __restrict__ wUu,  // [12nt][2kt][64]
    const float* __restrict__ bu,
    const half8* __restrict__ wWr,  // [24nt][2kt][64]
    const half8* __restrict__ wUr,  // [24nt][4kt][64]
    const float* __restrict__ br,
    int E, int M)
{
    __shared__ float smem[4][3][16 * 65];   // [wave][stage, agg0, agg1]
    __shared__ int skeys[4][16];

    const int wid = threadIdx.x >> 6;
    const int lane = threadIdx.x & 63;
    const int hi = lane >> 4;
    const int l15 = lane & 15;
    const int e0 = (blockIdx.x * 4 + wid) * 32;

    float* stage = smem[wid][0];
    float* agg0 = smem[wid][1];
    float* agg1 = smem[wid][2];
    int* skey = skeys[wid];

    // zero agg tiles (cols 0..63; col 64 is pad)
    #pragma unroll
    for (int m = 0; m < 16; ++m) {
        agg0[m * 65 + lane] = 0.0f;
        agg1[m * 65 + lane] = 0.0f;
    }

    // message-MLP weights, register resident
    half8 Bm[4][4];
    #pragma unroll
    for (int nt = 0; nt < 4; ++nt)
        #pragma unroll
        for (int kt = 0; kt < 4; ++kt)
            Bm[nt][kt] = wBm[(nt * 4 + kt) * 64 + lane];

    // ---- message phase (per group) ----
    #pragma unroll 1
    for (int g = 0; g < 2; ++g) {
        int a = e0 + g * 16;
        if (a >= E) continue;
        int b = min(a + 16, E);
        int mstart = off[a];
        int mend = (b == E) ? M : off[b];
        float* aggT = g ? agg1 : agg0;

        #pragma unroll 1
        for (int ch = 0; mstart + ch * 16 < mend; ++ch) {
            int mrow = mstart + ch * 16 + l15;
            bool mv = (mrow < mend);
            int mcl = min(mrow, mend - 1);
            int2 p = fs[mcl];
            const half8* fr = reinterpret_cast<const half8*>(hin + (size_t)p.x * D);
            const half8* sr = reinterpret_cast<const half8*>(hin + (size_t)p.y * D);
            half8 A[4];
            A[0] = fr[hi];
            A[1] = fr[4 + hi];
            A[2] = sr[hi];
            A[3] = sr[4 + hi];

            f32x4 acc[4];
            #pragma unroll
            for (int nt = 0; nt < 4; ++nt) acc[nt] = (f32x4){0.f, 0.f, 0.f, 0.f};
            #pragma unroll
            for (int nt = 0; nt < 4; ++nt)
                #pragma unroll
                for (int kt = 0; kt < 4; ++kt)
                    acc[nt] = __builtin_amdgcn_mfma_f32_16x16x32_f16(A[kt], Bm[nt][kt], acc[nt], 0, 0, 0);

            // selu epilogue -> stage tile
            #pragma unroll
            for (int nt = 0; nt < 4; ++nt) {
                int n = nt * 16 + l15;
                float bias = bm[n];
                #pragma unroll
                for (int r = 0; r < 4; ++r) {
                    float v = acc[nt][r] + bias;
                    v = (v > 0.0f) ? (SELU_SCALE * v)
                                   : (SELU_SCALE * SELU_ALPHA) * (__expf(v) - 1.0f);
                    stage[(hi * 4 + r) * 65 + n] = v;
                }
            }
            if (lane < 16) skey[lane] = mv ? (p.y - a) : -1;

            // segmented run-sum over the 16 rows (receiver-sorted)
            float run = 0.0f;
            int kprev = skey[0];
            #pragma unroll
            for (int m = 0; m < 16; ++m) {
                int km = skey[m];
                if (km != kprev) {
                    if (kprev >= 0) aggT[kprev * 65 + lane] += run;
                    run = 0.0f;
                    kprev = km;
                }
                run += stage[m * 65 + lane];
            }
            if (kprev >= 0) aggT[kprev * 65 + lane] += run;
        }
    }

    // ---- fragment loads for update GRU (+ readout prefetch) ----
    int ec[2];
    ec[0] = min(e0 + l15, E - 1);
    ec[1] = min(e0 + 16 + l15, E - 1);

    half8 AX[2][2], AHu[2][2], AHro[2][4];
    #pragma unroll
    for (int g = 0; g < 2; ++g) {
        float* aggT = g ? agg1 : agg0;
        #pragma unroll
        for (int kt = 0; kt < 2; ++kt) {
            const float* s = aggT + l15 * 65 + 32 * kt + 8 * hi;
            half8 ax;
            #pragma unroll
            for (int j = 0; j < 8; ++j) ax[j] = (_Float16)s[j];
            AX[g][kt] = ax;
            AHu[g][kt] = reinterpret_cast<const half8*>(hin + (size_t)ec[g] * D)[4 * kt + hi];
        }
        #pragma unroll
        for (int kt = 0; kt < 4; ++kt)
            AHro[g][kt] = reinterpret_cast<const half8*>(hro + (size_t)ec[g] * R)[4 * kt + hi];
    }

    // ---- phase 1: update GRU; h' -> hout + staged into agg tiles ----
    #pragma unroll 1
    for (int i = 0; i < 4; ++i) {
        half8 WBz[2], WBr[2], WBc[2], UBz[2], UBr[2], UBc[2];
        #pragma unroll
        for (int kt = 0; kt < 2; ++kt) {
            WBz[kt] = wWu[((0 + i) * 2 + kt) * 64 + lane];
            WBr[kt] = wWu[((4 + i) * 2 + kt) * 64 + lane];
            WBc[kt] = wWu[((8 + i) * 2 + kt) * 64 + lane];
            UBz[kt] = wUu[((0 + i) * 2 + kt) * 64 + lane];
            UBr[kt] = wUu[((4 + i) * 2 + kt) * 64 + lane];
            UBc[kt] = wUu[((8 + i) * 2 + kt) * 64 + lane];
        }
        int n = 16 * i + l15;
        float bz  = bu[n] + bu[192 + n];
        float brr = bu[64 + n] + bu[256 + n];
        float bx  = bu[128 + n];
        float bh  = bu[320 + n];

        #pragma unroll
        for (int g = 0; g < 2; ++g) {
            float* aggT = g ? agg1 : agg0;
            f32x4 az  = (f32x4){0.f, 0.f, 0.f, 0.f};
            f32x4 ar_ = (f32x4){0.f, 0.f, 0.f, 0.f};
            f32x4 acx = (f32x4){0.f, 0.f, 0.f, 0.f};
            f32x4 ach = (f32x4){0.f, 0.f, 0.f, 0.f};
            #pragma unroll
            for (int kt = 0; kt < 2; ++kt) {
                az  = __builtin_amdgcn_mfma_f32_16x16x32_f16(AX[g][kt], WBz[kt], az, 0, 0, 0);
                az  = __builtin_amdgcn_mfma_f32_16x16x32_f16(AHu[g][kt], UBz[kt], az, 0, 0, 0);
                ar_ = __builtin_amdgcn_mfma_f32_16x16x32_f16(AX[g][kt], WBr[kt], ar_, 0, 0, 0);
                ar_ = __builtin_amdgcn_mfma_f32_16x16x32_f16(AHu[g][kt], UBr[kt], ar_, 0, 0, 0);
                acx = __builtin_amdgcn_mfma_f32_16x16x32_f16(AX[g][kt], WBc[kt], acx, 0, 0, 0);
                ach = __builtin_amdgcn_mfma_f32_16x16x32_f16(AHu[g][kt], UBc[kt], ach, 0, 0, 0);
            }
            #pragma unroll
            for (int r = 0; r < 4; ++r) {
                int e = e0 + g * 16 + hi * 4 + r;
                int ecl = min(e, E - 1);
                float z = fast_sig(az[r] + bz);
                float rr = fast_sig(ar_[r] + brr);
                float c = fast_tanh(acx[r] + bx + rr * (ach[r] + bh));
                float hp = (float)hin[(size_t)ecl * D + n];
                float hn = z * hp + (1.0f - z) * c;
                aggT[(hi * 4 + r) * 65 + n] = hn;        // stage h' for ro phase
                if (e < E) hout[(size_t)e * D + n] = (_Float16)hn;
            }
        }
    }

    // h' fragments from the staged tiles
    half8 AXn[2][2];
    #pragma unroll
    for (int g = 0; g < 2; ++g) {
        float* aggT = g ? agg1 : agg0;
        #pragma unroll
        for (int kt = 0; kt < 2; ++kt) {
            const float* s = aggT + l15 * 65 + 32 * kt + 8 * hi;
            half8 ax;
            #pragma unroll
            for (int j = 0; j < 8; ++j) ax[j] = (_Float16)s[j];
            AXn[g][kt] = ax;
        }
    }

    // ---- phase 2: readout GRU, all 128 columns, in-place on hro ----
    #pragma unroll 1
    for (int it = 0; it < 8; ++it) {
        half8 WBz[2], WBr[2], WBx[2], UBz[4], UBr[4], UBh[4];
        #pragma unroll
        for (int kt = 0; kt < 2; ++kt) {
            WBz[kt] = wWr[((0 + it) * 2 + kt) * 64 + lane];
            WBr[kt] = wWr[((8 + it) * 2 + kt) * 64 + lane];
            WBx[kt] = wWr[((16 + it) * 2 + kt) * 64 + lane];
        }
        #pragma unroll
        for (int kt = 0; kt < 4; ++kt) {
            UBz[kt] = wUr[((0 + it) * 4 + kt) * 64 + lane];
            UBr[kt] = wUr[((8 + it) * 4 + kt) * 64 + lane];
            UBh[kt] = wUr[((16 + it) * 4 + kt) * 64 + lane];
        }
        int c = it * 16 + l15;
        float bz  = br[c] + br[384 + c];
        float brr = br[128 + c] + br[512 + c];
        float bx  = br[256 + c];
        float bh  = br[640 + c];

        #pragma unroll
        for (int g = 0; g < 2; ++g) {
            f32x4 az  = (f32x4){0.f, 0.f, 0.f, 0.f};
            f32x4 ar_ = (f32x4){0.f, 0.f, 0.f, 0.f};
            f32x4 acx = (f32x4){0.f, 0.f, 0.f, 0.f};
            f32x4 ach = (f32x4){0.f, 0.f, 0.f, 0.f};
            #pragma unroll
            for (int kt = 0; kt < 2; ++kt) {
                az  = __builtin_amdgcn_mfma_f32_16x16x32_f16(AXn[g][kt], WBz[kt], az, 0, 0, 0);
                ar_ = __builtin_amdgcn_mfma_f32_16x16x32_f16(AXn[g][kt], WBr[kt], ar_, 0, 0, 0);
                acx = __builtin_amdgcn_mfma_f32_16x16x32_f16(AXn[g][kt], WBx[kt], acx, 0, 0, 0);
            }
            #pragma unroll
            for (int kt = 0; kt < 4; ++kt) {
                az  = __builtin_amdgcn_mfma_f32_16x16x32_f16(AHro[g][kt], UBz[kt], az, 0, 0, 0);
                ar_ = __builtin_amdgcn_mfma_f32_16x16x32_f16(AHro[g][kt], UBr[kt], ar_, 0, 0, 0);
                ach = __builtin_amdgcn_mfma_f32_16x16x32_f16(AHro[g][kt], UBh[kt], ach, 0, 0, 0);
            }
            #pragma unroll
            for (int r = 0; r < 4; ++r) {
                int e = e0 + g * 16 + hi * 4 + r;
                int ecl = min(e, E - 1);
                float z = fast_sig(az[r] + bz);
                float rr = fast_sig(ar_[r] + brr);
                float cc = fast_tanh(acx[r] + bx + rr * (ach[r] + bh));
                float hp = (float)hro[(size_t)ecl * R + c];
                if (e < E) hro[(size_t)e * R + c] = (_Float16)(z * hp + (1.0f - z) * cc);
            }
        }
    }
}

// ---------------------------------------------------------------------------
// Output: out[g] = b_out + sum_{e: gid[e]==g} dot(hro[e], W_out)
// gids sorted -> wave-level segmented scan; sentinel g=-1 for OOB lanes.
// ---------------------------------------------------------------------------
__global__ void out_init_kernel(float* __restrict__ out, const float* __restrict__ b_out, int G) {
    int g = blockIdx.x * blockDim.x + threadIdx.x;
    if (g < G) out[g] = b_out[0];
}

__global__ __launch_bounds__(256) void out_kernel(
    const _Float16* __restrict__ hro,
    const int* __restrict__ gid,
    const float* __restrict__ Wout,
    float* __restrict__ out,
    int E)
{
    int e = blockIdx.x * 256 + threadIdx.x;
    int lane = threadIdx.x & 63;
    int ec = min(e, E - 1);
    const half8* hp = reinterpret_cast<const half8*>(hro + (size_t)ec * R);
    float s = 0.0f;
    #pragma unroll
    for (int kk = 0; kk < R / 8; ++kk) {
        half8 v = hp[kk];
        #pragma unroll
        for (int j = 0; j < 8; ++j)
            s = fmaf((float)v[j], Wout[kk * 8 + j], s);
    }
    bool valid = (e < E);
    if (!valid) s = 0.0f;
    int g = valid ? gid[ec] : -1;
    #pragma unroll
    for (int d = 1; d < 64; d <<= 1) {
        float t = __shfl_up(s, d);
        int kg = __shfl_up(g, d);
        if (lane >= d && kg == g) s += t;
    }
    int gnext = __shfl_down(g, 1);
    bool tail = (lane == 63) || (gnext != g);
    if (tail && valid) unsafeAtomicAdd(out + g, s);
}

// ---------------------------------------------------------------------------
extern "C" void kernel_launch(void* const* d_in, const int* in_sizes, int n_in,
                              void* d_out, int out_size, void* d_ws, size_t ws_size,
                              hipStream_t stream) {
    const float* link_state = (const float*)d_in[0];
    const int*   first      = (const int*)d_in[1];
    const int*   second     = (const int*)d_in[2];
    const int*   gids       = (const int*)d_in[3];
    const float* Wm         = (const float*)d_in[5];
    const float* bm         = (const float*)d_in[6];
    const float* Wu         = (const float*)d_in[7];
    const float* Uu         = (const float*)d_in[8];
    const float* bu         = (const float*)d_in[9];
    const float* Wr         = (const float*)d_in[10];
    const float* Ur         = (const float*)d_in[11];
    const float* brb        = (const float*)d_in[12];
    const float* Wout       = (const float*)d_in[13];
    const float* bout       = (const float*)d_in[14];

    const int E = in_sizes[0] / D;
    const int M = in_sizes[1];
    const int G = out_size;

    char* p = (char*)d_ws;
    auto carve = [&](size_t bytes) {
        void* r = (void*)p;
        p += (bytes + 255) & ~(size_t)255;
        return r;
    };
    _Float16*  hA   = (_Float16*)carve((size_t)E * D * 2);
    _Float16*  hB   = (_Float16*)carve((size_t)E * D * 2);
    _Float16*  hro  = (_Float16*)carve((size_t)E * R * 2);
    int*       perm = (int*)carve((size_t)M * 4);
    int2*      fs   = (int2*)carve((size_t)M * 8);
    int*       cnt  = (int*)carve((size_t)E * 4);
    int*       cur  = (int*)carve((size_t)E * 4);
    int*       off  = (int*)carve((size_t)(E + 1) * 4);
    int*       bsum = (int*)carve(4096 * 4);
    _Float16*  wWm  = (_Float16*)carve(8192 * 2);
    _Float16*  wWu  = (_Float16*)carve(12288 * 2);
    _Float16*  wUu  = (_Float16*)carve(12288 * 2);
    _Float16*  wWr  = (_Float16*)carve(24576 * 2);
    _Float16*  wUr  = (_Float16*)carve(49152 * 2);

    hipMemsetAsync(hro, 0, (size_t)E * R * 2, stream);
    hipMemsetAsync(cnt, 0, (size_t)E * 4, stream);
    hipMemsetAsync(cur, 0, (size_t)E * 4, stream);

    h16_init<<<(E * D + 255) / 256, 256, 0, stream>>>(link_state, hA, E * D);
    swizzle_all<<<dim3(192, 5), 256, 0, stream>>>(Wm, Wu, Uu, Wr, Ur,
                                                  wWm, wWu, wUu, wWr, wUr);

    const int NB = (E + 255) / 256;   // 391 for E=100k; scan_part handles <=1024
    hist_kernel<<<(M + 255) / 256, 256, 0, stream>>>(second, cnt, M);
    scan_bsum<<<NB, 256, 0, stream>>>(cnt, bsum, E);
    scan_part<<<1, 1024, 0, stream>>>(bsum, NB);
    scan_final<<<NB, 256, 0, stream>>>(cnt, bsum, off, E);
    scatter_kernel<<<(M + 255) / 256, 256, 0, stream>>>(second, off, cur, perm, M);
    fs_pack<<<(M + 255) / 256, 256, 0, stream>>>(first, second, perm, fs, M);

    const int e_blocks = (E + 127) / 128;

    _Float16* hin = hA;
    _Float16* hout = hB;
    for (int t = 0; t < NSTEPS; ++t) {
        step_fused<<<e_blocks, 256, 0, stream>>>(hin, hout, hro, fs, off,
                                                 (const half8*)wWm, bm,
                                                 (const half8*)wWu, (const half8*)wUu, bu,
                                                 (const half8*)wWr, (const half8*)wUr, brb,
                                                 E, M);
        _Float16* tmp = hin; hin = hout; hout = tmp;
    }

    out_init_kernel<<<(G + 255) / 256, 256, 0, stream>>>((float*)d_out, bout, G);
    out_kernel<<<(E + 255) / 256, 256, 0, stream>>>(hro, gids, Wout, (float*)d_out, E);
}

// Round 8
// 854.201 us; speedup vs baseline: 24.9730x; 1.2664x over previous
//
#include <hip/hip_runtime.h>
#include <hip/hip_bf16.h>

#define D 64
#define R 128
#define NSTEPS 8
#define SELU_SCALE 1.0507009873554805f
#define SELU_ALPHA 1.6732632423543772f
#define PAD 68   // floats per LDS tile row; 4*PAD = 16 mod 32 -> conflict-free

typedef _Float16 half8 __attribute__((ext_vector_type(8)));
typedef float f32x4 __attribute__((ext_vector_type(4)));

__device__ __forceinline__ float fast_sig(float x) {
    return __fdividef(1.0f, 1.0f + __expf(-x));
}
__device__ __forceinline__ float fast_tanh(float x) {
    float xc = fminf(fmaxf(x, -15.0f), 15.0f);
    float e = __expf(2.0f * xc);
    return 1.0f - __fdividef(2.0f, e + 1.0f);
}

// ---------------------------------------------------------------------------
// Prep: all 5 weight swizzles in ONE kernel. fp32 [K][N] -> fp16 MFMA
// B-fragment order: dst[((nt*KT+kt)*64+lane)*8+j] =
//   src[(32*kt + 8*(lane>>4) + j)*N + 16*nt + (lane&15)]
// ---------------------------------------------------------------------------
__global__ __launch_bounds__(256) void swizzle_all(
    const float* __restrict__ Wm, const float* __restrict__ Wu,
    const float* __restrict__ Uu, const float* __restrict__ Wr,
    const float* __restrict__ Ur,
    _Float16* __restrict__ wWm, _Float16* __restrict__ wWu,
    _Float16* __restrict__ wUu, _Float16* __restrict__ wWr,
    _Float16* __restrict__ wUr)
{
    const float* src; _Float16* dst; int K, N;
    switch (blockIdx.y) {
        case 0: src = Wm; dst = wWm; K = 128; N = 64;  break;
        case 1: src = Wu; dst = wWu; K = 64;  N = 192; break;
        case 2: src = Uu; dst = wUu; K = 64;  N = 192; break;
        case 3: src = Wr; dst = wWr; K = 64;  N = 384; break;
        default: src = Ur; dst = wUr; K = 128; N = 384; break;
    }
    int idx = blockIdx.x * 256 + threadIdx.x;
    int KT = K >> 5;
    int total = KT * (N >> 4) * 512;
    if (idx >= total) return;
    int j = idx & 7;
    int lane = (idx >> 3) & 63;
    int kt = (idx >> 9) % KT;
    int nt = idx / (512 * KT);
    int k = 32 * kt + 8 * (lane >> 4) + j;
    int n = 16 * nt + (lane & 15);
    dst[idx] = (_Float16)src[(size_t)k * N + n];
}

__global__ __launch_bounds__(256) void h16_init(const float* __restrict__ src,
                                                _Float16* __restrict__ dst, int n) {
    int i = blockIdx.x * 256 + threadIdx.x;
    if (i < n) dst[i] = (_Float16)src[i];
}

// ---------------------------------------------------------------------------
// CSR build: hist -> 3-kernel scan -> scatter -> fs pack
// ---------------------------------------------------------------------------
__global__ __launch_bounds__(256) void hist_kernel(const int* __restrict__ second,
                                                   int* __restrict__ cnt, int M) {
    int m = blockIdx.x * 256 + threadIdx.x;
    if (m < M) atomicAdd(&cnt[second[m]], 1);
}

__global__ __launch_bounds__(256) void scan_bsum(const int* __restrict__ cnt,
                                                 int* __restrict__ bsum, int E) {
    int i = blockIdx.x * 256 + threadIdx.x;
    int tid = threadIdx.x;
    int v = (i < E) ? cnt[i] : 0;
    __shared__ int s[256];
    s[tid] = v;
    __syncthreads();
    #pragma unroll
    for (int d = 1; d < 256; d <<= 1) {
        int t = (tid >= d) ? s[tid - d] : 0;
        __syncthreads();
        s[tid] += t;
        __syncthreads();
    }
    if (tid == 255) bsum[blockIdx.x] = s[255];
}

__global__ __launch_bounds__(1024) void scan_part(int* __restrict__ bsum, int NB) {
    int tid = threadIdx.x;
    __shared__ int s[1024];
    int v = (tid < NB) ? bsum[tid] : 0;
    s[tid] = v;
    __syncthreads();
    #pragma unroll
    for (int d = 1; d < 1024; d <<= 1) {
        int t = (tid >= d) ? s[tid - d] : 0;
        __syncthreads();
        s[tid] += t;
        __syncthreads();
    }
    if (tid < NB) bsum[tid] = s[tid] - v;   // exclusive
}

__global__ __launch_bounds__(256) void scan_final(const int* __restrict__ cnt,
                                                  const int* __restrict__ bsum,
                                                  int* __restrict__ off, int E) {
    int i = blockIdx.x * 256 + threadIdx.x;
    int tid = threadIdx.x;
    int v = (i < E) ? cnt[i] : 0;
    __shared__ int s[256];
    s[tid] = v;
    __syncthreads();
    #pragma unroll
    for (int d = 1; d < 256; d <<= 1) {
        int t = (tid >= d) ? s[tid - d] : 0;
        __syncthreads();
        s[tid] += t;
        __syncthreads();
    }
    if (i < E) off[i] = bsum[blockIdx.x] + s[tid] - v;
}

__global__ __launch_bounds__(256) void scatter_kernel(const int* __restrict__ second,
                                                      const int* __restrict__ off,
                                                      int* __restrict__ cur,
                                                      int* __restrict__ perm, int M) {
    int m = blockIdx.x * 256 + threadIdx.x;
    if (m < M) {
        int s = second[m];
        int p = atomicAdd(&cur[s], 1);
        perm[off[s] + p] = m;
    }
}

__global__ __launch_bounds__(256) void fs_pack(const int* __restrict__ first,
                                               const int* __restrict__ second,
                                               const int* __restrict__ perm,
                                               int2* __restrict__ fs, int M) {
    int m = blockIdx.x * 256 + threadIdx.x;
    if (m < M) {
        int pm = perm[m];
        fs[m] = make_int2(first[pm], second[pm]);
    }
}

// ---------------------------------------------------------------------------
// Mega-step kernel: msg + update-GRU + readout-GRU, one launch per MP step.
// Wave owns 16 edges (one MFMA row-tile). Per wave:
//  - messages [off[e0], off[e0+16]) are CSR-contiguous; 16-msg MFMA chunks,
//    selu -> LDS stage tile, segmented run-sum -> LDS agg tile.
//  - agg tile -> AX fragments; update GRU; h' -> hout + staged in agg tile.
//  - readout GRU (all 128 cols) in-place on hro.
// Tiles per-wave, rows padded to PAD=68 f32 -> conflict-free; no barriers.
// hin/hout ping-pong across steps keeps message gathers race-free.
// ---------------------------------------------------------------------------
__global__ __launch_bounds__(256) void step_fused(
    const _Float16* __restrict__ hin,
    _Float16* __restrict__ hout,
    _Float16* hro,
    const int2* __restrict__ fs,
    const int* __restrict__ off,
    const half8* __restrict__ wBm,  // [4nt][4kt][64]
    const float* __restrict__ bm,
    const half8* __restrict__ wWu,  // [12nt][2kt][64]
    const half8* __restrict__ wUu,  // [12nt][2kt][64]
    const float* __restrict__ bu,
    const half8* __restrict__ wWr,  // [24nt][2kt][64]
    const half8* __restrict__ wUr,  // [24nt][4kt][64]
    const float* __restrict__ br,
    int E, int M)
{
    __shared__ float smem[4][2][16 * PAD];   // [wave][stage, agg]
    __shared__ int skeys[4][16];

    const int wid = threadIdx.x >> 6;
    const int lane = threadIdx.x & 63;
    const int hi = lane >> 4;
    const int l15 = lane & 15;
    const int e0 = (blockIdx.x * 4 + wid) * 16;

    float* stage = smem[wid][0];
    float* aggT = smem[wid][1];
    int* skey = skeys[wid];

    // zero agg tile (cols 0..63; rest is pad)
    #pragma unroll
    for (int m = 0; m < 16; ++m)
        aggT[m * PAD + lane] = 0.0f;

    // message-MLP weights, register resident
    half8 Bm[4][4];
    #pragma unroll
    for (int nt = 0; nt < 4; ++nt)
        #pragma unroll
        for (int kt = 0; kt < 4; ++kt)
            Bm[nt][kt] = wBm[(nt * 4 + kt) * 64 + lane];

    // ---- message phase ----
    if (e0 < E) {
        int b = min(e0 + 16, E);
        int mstart = off[e0];
        int mend = (b == E) ? M : off[b];

        #pragma unroll 1
        for (int ch = 0; mstart + ch * 16 < mend; ++ch) {
            int mrow = mstart + ch * 16 + l15;
            bool mv = (mrow < mend);
            int mcl = min(mrow, mend - 1);
            int2 p = fs[mcl];
            const half8* fr = reinterpret_cast<const half8*>(hin + (size_t)p.x * D);
            const half8* sr = reinterpret_cast<const half8*>(hin + (size_t)p.y * D);
            half8 A[4];
            A[0] = fr[hi];
            A[1] = fr[4 + hi];
            A[2] = sr[hi];
            A[3] = sr[4 + hi];

            f32x4 acc[4];
            #pragma unroll
            for (int nt = 0; nt < 4; ++nt) acc[nt] = (f32x4){0.f, 0.f, 0.f, 0.f};
            #pragma unroll
            for (int nt = 0; nt < 4; ++nt)
                #pragma unroll
                for (int kt = 0; kt < 4; ++kt)
                    acc[nt] = __builtin_amdgcn_mfma_f32_16x16x32_f16(A[kt], Bm[nt][kt], acc[nt], 0, 0, 0);

            // selu epilogue -> stage tile
            #pragma unroll
            for (int nt = 0; nt < 4; ++nt) {
                int n = nt * 16 + l15;
                float bias = bm[n];
                #pragma unroll
                for (int r = 0; r < 4; ++r) {
                    float v = acc[nt][r] + bias;
                    v = (v > 0.0f) ? (SELU_SCALE * v)
                                   : (SELU_SCALE * SELU_ALPHA) * (__expf(v) - 1.0f);
                    stage[(hi * 4 + r) * PAD + n] = v;
                }
            }
            if (lane < 16) skey[lane] = mv ? (p.y - e0) : -1;

            // segmented run-sum over the 16 rows (receiver-sorted)
            float run = 0.0f;
            int kprev = skey[0];
            #pragma unroll
            for (int m = 0; m < 16; ++m) {
                int km = skey[m];
                if (km != kprev) {
                    if (kprev >= 0) aggT[kprev * PAD + lane] += run;
                    run = 0.0f;
                    kprev = km;
                }
                run += stage[m * PAD + lane];
            }
            if (kprev >= 0) aggT[kprev * PAD + lane] += run;
        }
    }

    // ---- fragment loads for update GRU (+ readout prefetch) ----
    const int ec = min(e0 + l15, E - 1);

    half8 AX[2], AHu[2], AHro[4];
    #pragma unroll
    for (int kt = 0; kt < 2; ++kt) {
        const float* s = aggT + l15 * PAD + 32 * kt + 8 * hi;
        half8 ax;
        #pragma unroll
        for (int j = 0; j < 8; ++j) ax[j] = (_Float16)s[j];
        AX[kt] = ax;
        AHu[kt] = reinterpret_cast<const half8*>(hin + (size_t)ec * D)[4 * kt + hi];
    }
    #pragma unroll
    for (int kt = 0; kt < 4; ++kt)
        AHro[kt] = reinterpret_cast<const half8*>(hro + (size_t)ec * R)[4 * kt + hi];

    // ---- phase 1: update GRU; h' -> hout + staged into agg tile ----
    #pragma unroll 1
    for (int i = 0; i < 4; ++i) {
        half8 WBz[2], WBr[2], WBc[2], UBz[2], UBr[2], UBc[2];
        #pragma unroll
        for (int kt = 0; kt < 2; ++kt) {
            WBz[kt] = wWu[((0 + i) * 2 + kt) * 64 + lane];
            WBr[kt] = wWu[((4 + i) * 2 + kt) * 64 + lane];
            WBc[kt] = wWu[((8 + i) * 2 + kt) * 64 + lane];
            UBz[kt] = wUu[((0 + i) * 2 + kt) * 64 + lane];
            UBr[kt] = wUu[((4 + i) * 2 + kt) * 64 + lane];
            UBc[kt] = wUu[((8 + i) * 2 + kt) * 64 + lane];
        }
        int n = 16 * i + l15;
        float bz  = bu[n] + bu[192 + n];
        float brr = bu[64 + n] + bu[256 + n];
        float bx  = bu[128 + n];
        float bh  = bu[320 + n];

        f32x4 az  = (f32x4){0.f, 0.f, 0.f, 0.f};
        f32x4 ar_ = (f32x4){0.f, 0.f, 0.f, 0.f};
        f32x4 acx = (f32x4){0.f, 0.f, 0.f, 0.f};
        f32x4 ach = (f32x4){0.f, 0.f, 0.f, 0.f};
        #pragma unroll
        for (int kt = 0; kt < 2; ++kt) {
            az  = __builtin_amdgcn_mfma_f32_16x16x32_f16(AX[kt], WBz[kt], az, 0, 0, 0);
            az  = __builtin_amdgcn_mfma_f32_16x16x32_f16(AHu[kt], UBz[kt], az, 0, 0, 0);
            ar_ = __builtin_amdgcn_mfma_f32_16x16x32_f16(AX[kt], WBr[kt], ar_, 0, 0, 0);
            ar_ = __builtin_amdgcn_mfma_f32_16x16x32_f16(AHu[kt], UBr[kt], ar_, 0, 0, 0);
            acx = __builtin_amdgcn_mfma_f32_16x16x32_f16(AX[kt], WBc[kt], acx, 0, 0, 0);
            ach = __builtin_amdgcn_mfma_f32_16x16x32_f16(AHu[kt], UBc[kt], ach, 0, 0, 0);
        }
        #pragma unroll
        for (int r = 0; r < 4; ++r) {
            int e = e0 + hi * 4 + r;
            int ecl = min(e, E - 1);
            float z = fast_sig(az[r] + bz);
            float rr = fast_sig(ar_[r] + brr);
            float c = fast_tanh(acx[r] + bx + rr * (ach[r] + bh));
            float hp = (float)hin[(size_t)ecl * D + n];
            float hn = z * hp + (1.0f - z) * c;
            aggT[(hi * 4 + r) * PAD + n] = hn;        // stage h' for ro phase
            if (e < E) hout[(size_t)e * D + n] = (_Float16)hn;
        }
    }

    // h' fragments from the staged tile
    half8 AXn[2];
    #pragma unroll
    for (int kt = 0; kt < 2; ++kt) {
        const float* s = aggT + l15 * PAD + 32 * kt + 8 * hi;
        half8 ax;
        #pragma unroll
        for (int j = 0; j < 8; ++j) ax[j] = (_Float16)s[j];
        AXn[kt] = ax;
    }

    // ---- phase 2: readout GRU, all 128 columns, in-place on hro ----
    #pragma unroll 1
    for (int it = 0; it < 8; ++it) {
        half8 WBz[2], WBr[2], WBx[2], UBz[4], UBr[4], UBh[4];
        #pragma unroll
        for (int kt = 0; kt < 2; ++kt) {
            WBz[kt] = wWr[((0 + it) * 2 + kt) * 64 + lane];
            WBr[kt] = wWr[((8 + it) * 2 + kt) * 64 + lane];
            WBx[kt] = wWr[((16 + it) * 2 + kt) * 64 + lane];
        }
        #pragma unroll
        for (int kt = 0; kt < 4; ++kt) {
            UBz[kt] = wUr[((0 + it) * 4 + kt) * 64 + lane];
            UBr[kt] = wUr[((8 + it) * 4 + kt) * 64 + lane];
            UBh[kt] = wUr[((16 + it) * 4 + kt) * 64 + lane];
        }
        int c = it * 16 + l15;
        float bz  = br[c] + br[384 + c];
        float brr = br[128 + c] + br[512 + c];
        float bx  = br[256 + c];
        float bh  = br[640 + c];

        f32x4 az  = (f32x4){0.f, 0.f, 0.f, 0.f};
        f32x4 ar_ = (f32x4){0.f, 0.f, 0.f, 0.f};
        f32x4 acx = (f32x4){0.f, 0.f, 0.f, 0.f};
        f32x4 ach = (f32x4){0.f, 0.f, 0.f, 0.f};
        #pragma unroll
        for (int kt = 0; kt < 2; ++kt) {
            az  = __builtin_amdgcn_mfma_f32_16x16x32_f16(AXn[kt], WBz[kt], az, 0, 0, 0);
            ar_ = __builtin_amdgcn_mfma_f32_16x16x32_f16(AXn[kt], WBr[kt], ar_, 0, 0, 0);
            acx = __builtin_amdgcn_mfma_f32_16x16x32_f16(AXn[kt], WBx[kt], acx, 0, 0, 0);
        }
        #pragma unroll
        for (int kt = 0; kt < 4; ++kt) {
            az  = __builtin_amdgcn_mfma_f32_16x16x32_f16(AHro[kt], UBz[kt], az, 0, 0, 0);
            ar_ = __builtin_amdgcn_mfma_f32_16x16x32_f16(AHro[kt], UBr[kt], ar_, 0, 0, 0);
            ach = __builtin_amdgcn_mfma_f32_16x16x32_f16(AHro[kt], UBh[kt], ach, 0, 0, 0);
        }
        #pragma unroll
        for (int r = 0; r < 4; ++r) {
            int e = e0 + hi * 4 + r;
            int ecl = min(e, E - 1);
            float z = fast_sig(az[r] + bz);
            float rr = fast_sig(ar_[r] + brr);
            float cc = fast_tanh(acx[r] + bx + rr * (ach[r] + bh));
            float hp = (float)hro[(size_t)ecl * R + c];
            if (e < E) hro[(size_t)e * R + c] = (_Float16)(z * hp + (1.0f - z) * cc);
        }
    }
}

// ---------------------------------------------------------------------------
// Output: out[g] = b_out + sum_{e: gid[e]==g} dot(hro[e], W_out)
// gids sorted -> wave-level segmented scan; sentinel g=-1 for OOB lanes.
// ---------------------------------------------------------------------------
__global__ void out_init_kernel(float* __restrict__ out, const float* __restrict__ b_out, int G) {
    int g = blockIdx.x * blockDim.x + threadIdx.x;
    if (g < G) out[g] = b_out[0];
}

__global__ __launch_bounds__(256) void out_kernel(
    const _Float16* __restrict__ hro,
    const int* __restrict__ gid,
    const float* __restrict__ Wout,
    float* __restrict__ out,
    int E)
{
    int e = blockIdx.x * 256 + threadIdx.x;
    int lane = threadIdx.x & 63;
    int ec = min(e, E - 1);
    const half8* hp = reinterpret_cast<const half8*>(hro + (size_t)ec * R);
    float s = 0.0f;
    #pragma unroll
    for (int kk = 0; kk < R / 8; ++kk) {
        half8 v = hp[kk];
        #pragma unroll
        for (int j = 0; j < 8; ++j)
            s = fmaf((float)v[j], Wout[kk * 8 + j], s);
    }
    bool valid = (e < E);
    if (!valid) s = 0.0f;
    int g = valid ? gid[ec] : -1;
    #pragma unroll
    for (int d = 1; d < 64; d <<= 1) {
        float t = __shfl_up(s, d);
        int kg = __shfl_up(g, d);
        if (lane >= d && kg == g) s += t;
    }
    int gnext = __shfl_down(g, 1);
    bool tail = (lane == 63) || (gnext != g);
    if (tail && valid) unsafeAtomicAdd(out + g, s);
}

// ---------------------------------------------------------------------------
extern "C" void kernel_launch(void* const* d_in, const int* in_sizes, int n_in,
                              void* d_out, int out_size, void* d_ws, size_t ws_size,
                              hipStream_t stream) {
    const float* link_state = (const float*)d_in[0];
    const int*   first      = (const int*)d_in[1];
    const int*   second     = (const int*)d_in[2];
    const int*   gids       = (const int*)d_in[3];
    const float* Wm         = (const float*)d_in[5];
    const float* bm         = (const float*)d_in[6];
    const float* Wu         = (const float*)d_in[7];
    const float* Uu         = (const float*)d_in[8];
    const float* bu         = (const float*)d_in[9];
    const float* Wr         = (const float*)d_in[10];
    const float* Ur         = (const float*)d_in[11];
    const float* brb        = (const float*)d_in[12];
    const float* Wout       = (const float*)d_in[13];
    const float* bout       = (const float*)d_in[14];

    const int E = in_sizes[0] / D;
    const int M = in_sizes[1];
    const int G = out_size;

    char* p = (char*)d_ws;
    auto carve = [&](size_t bytes) {
        void* r = (void*)p;
        p += (bytes + 255) & ~(size_t)255;
        return r;
    };
    _Float16*  hA   = (_Float16*)carve((size_t)E * D * 2);
    _Float16*  hB   = (_Float16*)carve((size_t)E * D * 2);
    _Float16*  hro  = (_Float16*)carve((size_t)E * R * 2);
    int*       perm = (int*)carve((size_t)M * 4);
    int2*      fs   = (int2*)carve((size_t)M * 8);
    int*       cnt  = (int*)carve((size_t)E * 4);
    int*       cur  = (int*)carve((size_t)E * 4);
    int*       off  = (int*)carve((size_t)(E + 1) * 4);
    int*       bsum = (int*)carve(4096 * 4);
    _Float16*  wWm  = (_Float16*)carve(8192 * 2);
    _Float16*  wWu  = (_Float16*)carve(12288 * 2);
    _Float16*  wUu  = (_Float16*)carve(12288 * 2);
    _Float16*  wWr  = (_Float16*)carve(24576 * 2);
    _Float16*  wUr  = (_Float16*)carve(49152 * 2);

    hipMemsetAsync(hro, 0, (size_t)E * R * 2, stream);
    hipMemsetAsync(cnt, 0, (size_t)E * 4, stream);
    hipMemsetAsync(cur, 0, (size_t)E * 4, stream);

    h16_init<<<(E * D + 255) / 256, 256, 0, stream>>>(link_state, hA, E * D);
    swizzle_all<<<dim3(192, 5), 256, 0, stream>>>(Wm, Wu, Uu, Wr, Ur,
                                                  wWm, wWu, wUu, wWr, wUr);

    const int NB = (E + 255) / 256;   // 391 for E=100k; scan_part handles <=1024
    hist_kernel<<<(M + 255) / 256, 256, 0, stream>>>(second, cnt, M);
    scan_bsum<<<NB, 256, 0, stream>>>(cnt, bsum, E);
    scan_part<<<1, 1024, 0, stream>>>(bsum, NB);
    scan_final<<<NB, 256, 0, stream>>>(cnt, bsum, off, E);
    scatter_kernel<<<(M + 255) / 256, 256, 0, stream>>>(second, off, cur, perm, M);
    fs_pack<<<(M + 255) / 256, 256, 0, stream>>>(first, second, perm, fs, M);

    const int e_blocks = (E + 63) / 64;   // 4 waves x 16 edges per block

    _Float16* hin = hA;
    _Float16* hout = hB;
    for (int t = 0; t < NSTEPS; ++t) {
        step_fused<<<e_blocks, 256, 0, stream>>>(hin, hout, hro, fs, off,
                                                 (const half8*)wWm, bm,
                                                 (const half8*)wWu, (const half8*)wUu, bu,
                                                 (const half8*)wWr, (const half8*)wUr, brb,
                                                 E, M);
        _Float16* tmp = hin; hin = hout; hout = tmp;
    }

    out_init_kernel<<<(G + 255) / 256, 256, 0, stream>>>((float*)d_out, bout, G);
    out_kernel<<<(E + 255) / 256, 256, 0, stream>>>(hro, gids, Wout, (float*)d_out, E);
}

// Round 9
// 851.278 us; speedup vs baseline: 25.0588x; 1.0034x over previous
//
#include <hip/hip_runtime.h>
#include <hip/hip_bf16.h>

#define D 64
#define R 128
#define NSTEPS 8
#define SELU_SCALE 1.0507009873554805f
#define SELU_ALPHA 1.6732632423543772f
#define PADH 72   // fp16 elems per LDS tile row; 144B stride = 9 x 16B -> uniform bank-quad spread

typedef _Float16 half8 __attribute__((ext_vector_type(8)));
typedef float f32x4 __attribute__((ext_vector_type(4)));

__device__ __forceinline__ float fast_sig(float x) {
    return __fdividef(1.0f, 1.0f + __expf(-x));
}
__device__ __forceinline__ float fast_tanh(float x) {
    float xc = fminf(fmaxf(x, -15.0f), 15.0f);
    float e = __expf(2.0f * xc);
    return 1.0f - __fdividef(2.0f, e + 1.0f);
}

// ---------------------------------------------------------------------------
// Prep: all 5 weight swizzles in ONE kernel. fp32 [K][N] -> fp16 MFMA
// B-fragment order: dst[((nt*KT+kt)*64+lane)*8+j] =
//   src[(32*kt + 8*(lane>>4) + j)*N + 16*nt + (lane&15)]
// ---------------------------------------------------------------------------
__global__ __launch_bounds__(256) void swizzle_all(
    const float* __restrict__ Wm, const float* __restrict__ Wu,
    const float* __restrict__ Uu, const float* __restrict__ Wr,
    const float* __restrict__ Ur,
    _Float16* __restrict__ wWm, _Float16* __restrict__ wWu,
    _Float16* __restrict__ wUu, _Float16* __restrict__ wWr,
    _Float16* __restrict__ wUr)
{
    const float* src; _Float16* dst; int K, N;
    switch (blockIdx.y) {
        case 0: src = Wm; dst = wWm; K = 128; N = 64;  break;
        case 1: src = Wu; dst = wWu; K = 64;  N = 192; break;
        case 2: src = Uu; dst = wUu; K = 64;  N = 192; break;
        case 3: src = Wr; dst = wWr; K = 64;  N = 384; break;
        default: src = Ur; dst = wUr; K = 128; N = 384; break;
    }
    int idx = blockIdx.x * 256 + threadIdx.x;
    int KT = K >> 5;
    int total = KT * (N >> 4) * 512;
    if (idx >= total) return;
    int j = idx & 7;
    int lane = (idx >> 3) & 63;
    int kt = (idx >> 9) % KT;
    int nt = idx / (512 * KT);
    int k = 32 * kt + 8 * (lane >> 4) + j;
    int n = 16 * nt + (lane & 15);
    dst[idx] = (_Float16)src[(size_t)k * N + n];
}

__global__ __launch_bounds__(256) void h16_init(const float* __restrict__ src,
                                                _Float16* __restrict__ dst, int n) {
    int i = blockIdx.x * 256 + threadIdx.x;
    if (i < n) dst[i] = (_Float16)src[i];
}

// ---------------------------------------------------------------------------
// CSR build: hist -> 3-kernel scan -> scatter -> fs pack
// ---------------------------------------------------------------------------
__global__ __launch_bounds__(256) void hist_kernel(const int* __restrict__ second,
                                                   int* __restrict__ cnt, int M) {
    int m = blockIdx.x * 256 + threadIdx.x;
    if (m < M) atomicAdd(&cnt[second[m]], 1);
}

__global__ __launch_bounds__(256) void scan_bsum(const int* __restrict__ cnt,
                                                 int* __restrict__ bsum, int E) {
    int i = blockIdx.x * 256 + threadIdx.x;
    int tid = threadIdx.x;
    int v = (i < E) ? cnt[i] : 0;
    __shared__ int s[256];
    s[tid] = v;
    __syncthreads();
    #pragma unroll
    for (int d = 1; d < 256; d <<= 1) {
        int t = (tid >= d) ? s[tid - d] : 0;
        __syncthreads();
        s[tid] += t;
        __syncthreads();
    }
    if (tid == 255) bsum[blockIdx.x] = s[255];
}

__global__ __launch_bounds__(1024) void scan_part(int* __restrict__ bsum, int NB) {
    int tid = threadIdx.x;
    __shared__ int s[1024];
    int v = (tid < NB) ? bsum[tid] : 0;
    s[tid] = v;
    __syncthreads();
    #pragma unroll
    for (int d = 1; d < 1024; d <<= 1) {
        int t = (tid >= d) ? s[tid - d] : 0;
        __syncthreads();
        s[tid] += t;
        __syncthreads();
    }
    if (tid < NB) bsum[tid] = s[tid] - v;   // exclusive
}

__global__ __launch_bounds__(256) void scan_final(const int* __restrict__ cnt,
                                                  const int* __restrict__ bsum,
                                                  int* __restrict__ off, int E) {
    int i = blockIdx.x * 256 + threadIdx.x;
    int tid = threadIdx.x;
    int v = (i < E) ? cnt[i] : 0;
    __shared__ int s[256];
    s[tid] = v;
    __syncthreads();
    #pragma unroll
    for (int d = 1; d < 256; d <<= 1) {
        int t = (tid >= d) ? s[tid - d] : 0;
        __syncthreads();
        s[tid] += t;
        __syncthreads();
    }
    if (i < E) off[i] = bsum[blockIdx.x] + s[tid] - v;
}

__global__ __launch_bounds__(256) void scatter_kernel(const int* __restrict__ second,
                                                      const int* __restrict__ off,
                                                      int* __restrict__ cur,
                                                      int* __restrict__ perm, int M) {
    int m = blockIdx.x * 256 + threadIdx.x;
    if (m < M) {
        int s = second[m];
        int p = atomicAdd(&cur[s], 1);
        perm[off[s] + p] = m;
    }
}

__global__ __launch_bounds__(256) void fs_pack(const int* __restrict__ first,
                                               const int* __restrict__ second,
                                               const int* __restrict__ perm,
                                               int2* __restrict__ fs, int M) {
    int m = blockIdx.x * 256 + threadIdx.x;
    if (m < M) {
        int pm = perm[m];
        fs[m] = make_int2(first[pm], second[pm]);
    }
}

// ---------------------------------------------------------------------------
// Mega-step kernel: msg + update-GRU + readout-GRU, one launch per MP step.
// Wave owns 16 edges. fp16 LDS tiles (stage, agg) with 72-elem row pitch:
// A-fragments are single ds_read_b128 (no scalar cvt/pack). agg accumulated
// in fp16 (RMW ~1-2x/edge). h' staged fp16 in agg tile for the ro phase.
// Per-wave tiles, no barriers. hin/hout ping-pong across steps.
// ---------------------------------------------------------------------------
__global__ __launch_bounds__(256) void step_fused(
    const _Float16* __restrict__ hin,
    _Float16* __restrict__ hout,
    _Float16* hro,
    const int2* __restrict__ fs,
    const int* __restrict__ off,
    const half8* __restrict__ wBm,  // [4nt][4kt][64]
    const float* __restrict__ bm,
    const half8* __restrict__ wWu,  // [12nt][2kt][64]
    const half8* __restrict__ wUu,  // [12nt][2kt][64]
    const float* __restrict__ bu,
    const half8* __restrict__ wWr,  // [24nt][2kt][64]
    const half8* __restrict__ wUr,  // [24nt][4kt][64]
    const float* __restrict__ br,
    int E, int M)
{
    __shared__ _Float16 smem[4][2][16 * PADH];   // [wave][stage, agg]
    __shared__ int skeys[4][16];

    const int wid = threadIdx.x >> 6;
    const int lane = threadIdx.x & 63;
    const int hi = lane >> 4;
    const int l15 = lane & 15;
    const int e0 = (blockIdx.x * 4 + wid) * 16;

    _Float16* stageH = smem[wid][0];
    _Float16* aggH = smem[wid][1];
    int* skey = skeys[wid];

    // zero agg tile via 32-bit writes: 16*36 dwords = 9 * 64 lanes
    {
        unsigned int* az = (unsigned int*)aggH;
        #pragma unroll
        for (int i = 0; i < 9; ++i) az[i * 64 + lane] = 0u;
    }

    // message-MLP weights, register resident
    half8 Bm[4][4];
    #pragma unroll
    for (int nt = 0; nt < 4; ++nt)
        #pragma unroll
        for (int kt = 0; kt < 4; ++kt)
            Bm[nt][kt] = wBm[(nt * 4 + kt) * 64 + lane];

    // ---- message phase ----
    if (e0 < E) {
        int b = min(e0 + 16, E);
        int mstart = off[e0];
        int mend = (b == E) ? M : off[b];

        #pragma unroll 1
        for (int ch = 0; mstart + ch * 16 < mend; ++ch) {
            int mrow = mstart + ch * 16 + l15;
            bool mv = (mrow < mend);
            int mcl = min(mrow, mend - 1);
            int2 p = fs[mcl];
            const half8* fr = reinterpret_cast<const half8*>(hin + (size_t)p.x * D);
            const half8* sr = reinterpret_cast<const half8*>(hin + (size_t)p.y * D);
            half8 A[4];
            A[0] = fr[hi];
            A[1] = fr[4 + hi];
            A[2] = sr[hi];
            A[3] = sr[4 + hi];

            f32x4 acc[4];
            #pragma unroll
            for (int nt = 0; nt < 4; ++nt) acc[nt] = (f32x4){0.f, 0.f, 0.f, 0.f};
            #pragma unroll
            for (int nt = 0; nt < 4; ++nt)
                #pragma unroll
                for (int kt = 0; kt < 4; ++kt)
                    acc[nt] = __builtin_amdgcn_mfma_f32_16x16x32_f16(A[kt], Bm[nt][kt], acc[nt], 0, 0, 0);

            // selu epilogue -> fp16 stage tile
            #pragma unroll
            for (int nt = 0; nt < 4; ++nt) {
                int n = nt * 16 + l15;
                float bias = bm[n];
                #pragma unroll
                for (int r = 0; r < 4; ++r) {
                    float v = acc[nt][r] + bias;
                    v = (v > 0.0f) ? (SELU_SCALE * v)
                                   : (SELU_SCALE * SELU_ALPHA) * (__expf(v) - 1.0f);
                    stageH[(hi * 4 + r) * PADH + n] = (_Float16)v;
                }
            }
            if (lane < 16) skey[lane] = mv ? (p.y - e0) : -1;

            // segmented run-sum over the 16 rows (receiver-sorted), fp16
            _Float16 run = (_Float16)0.0f;
            int kprev = skey[0];
            #pragma unroll
            for (int m = 0; m < 16; ++m) {
                int km = skey[m];
                if (km != kprev) {
                    if (kprev >= 0) aggH[kprev * PADH + lane] += run;
                    run = (_Float16)0.0f;
                    kprev = km;
                }
                run += stageH[m * PADH + lane];
            }
            if (kprev >= 0) aggH[kprev * PADH + lane] += run;
        }
    }

    // ---- fragment loads for update GRU (+ readout prefetch) ----
    const int ec = min(e0 + l15, E - 1);

    half8 AX[2], AHu[2], AHro[4];
    #pragma unroll
    for (int kt = 0; kt < 2; ++kt) {
        AX[kt] = *reinterpret_cast<const half8*>(&aggH[l15 * PADH + 32 * kt + 8 * hi]);
        AHu[kt] = reinterpret_cast<const half8*>(hin + (size_t)ec * D)[4 * kt + hi];
    }
    #pragma unroll
    for (int kt = 0; kt < 4; ++kt)
        AHro[kt] = reinterpret_cast<const half8*>(hro + (size_t)ec * R)[4 * kt + hi];

    // ---- phase 1: update GRU; h' -> hout + staged fp16 into agg tile ----
    #pragma unroll 1
    for (int i = 0; i < 4; ++i) {
        half8 WBz[2], WBr[2], WBc[2], UBz[2], UBr[2], UBc[2];
        #pragma unroll
        for (int kt = 0; kt < 2; ++kt) {
            WBz[kt] = wWu[((0 + i) * 2 + kt) * 64 + lane];
            WBr[kt] = wWu[((4 + i) * 2 + kt) * 64 + lane];
            WBc[kt] = wWu[((8 + i) * 2 + kt) * 64 + lane];
            UBz[kt] = wUu[((0 + i) * 2 + kt) * 64 + lane];
            UBr[kt] = wUu[((4 + i) * 2 + kt) * 64 + lane];
            UBc[kt] = wUu[((8 + i) * 2 + kt) * 64 + lane];
        }
        int n = 16 * i + l15;
        float bz  = bu[n] + bu[192 + n];
        float brr = bu[64 + n] + bu[256 + n];
        float bx  = bu[128 + n];
        float bh  = bu[320 + n];

        f32x4 az  = (f32x4){0.f, 0.f, 0.f, 0.f};
        f32x4 ar_ = (f32x4){0.f, 0.f, 0.f, 0.f};
        f32x4 acx = (f32x4){0.f, 0.f, 0.f, 0.f};
        f32x4 ach = (f32x4){0.f, 0.f, 0.f, 0.f};
        #pragma unroll
        for (int kt = 0; kt < 2; ++kt) {
            az  = __builtin_amdgcn_mfma_f32_16x16x32_f16(AX[kt], WBz[kt], az, 0, 0, 0);
            az  = __builtin_amdgcn_mfma_f32_16x16x32_f16(AHu[kt], UBz[kt], az, 0, 0, 0);
            ar_ = __builtin_amdgcn_mfma_f32_16x16x32_f16(AX[kt], WBr[kt], ar_, 0, 0, 0);
            ar_ = __builtin_amdgcn_mfma_f32_16x16x32_f16(AHu[kt], UBr[kt], ar_, 0, 0, 0);
            acx = __builtin_amdgcn_mfma_f32_16x16x32_f16(AX[kt], WBc[kt], acx, 0, 0, 0);
            ach = __builtin_amdgcn_mfma_f32_16x16x32_f16(AHu[kt], UBc[kt], ach, 0, 0, 0);
        }
        #pragma unroll
        for (int r = 0; r < 4; ++r) {
            int e = e0 + hi * 4 + r;
            int ecl = min(e, E - 1);
            float z = fast_sig(az[r] + bz);
            float rr = fast_sig(ar_[r] + brr);
            float c = fast_tanh(acx[r] + bx + rr * (ach[r] + bh));
            float hp = (float)hin[(size_t)ecl * D + n];
            float hn = z * hp + (1.0f - z) * c;
            _Float16 hn16 = (_Float16)hn;
            aggH[(hi * 4 + r) * PADH + n] = hn16;     // stage h' for ro phase
            if (e < E) hout[(size_t)e * D + n] = hn16;
        }
    }

    // h' fragments from the staged tile (single b128 reads)
    half8 AXn[2];
    #pragma unroll
    for (int kt = 0; kt < 2; ++kt)
        AXn[kt] = *reinterpret_cast<const half8*>(&aggH[l15 * PADH + 32 * kt + 8 * hi]);

    // ---- phase 2: readout GRU, all 128 columns, in-place on hro ----
    #pragma unroll 1
    for (int it = 0; it < 8; ++it) {
        half8 WBz[2], WBr[2], WBx[2], UBz[4], UBr[4], UBh[4];
        #pragma unroll
        for (int kt = 0; kt < 2; ++kt) {
            WBz[kt] = wWr[((0 + it) * 2 + kt) * 64 + lane];
            WBr[kt] = wWr[((8 + it) * 2 + kt) * 64 + lane];
            WBx[kt] = wWr[((16 + it) * 2 + kt) * 64 + lane];
        }
        #pragma unroll
        for (int kt = 0; kt < 4; ++kt) {
            UBz[kt] = wUr[((0 + it) * 4 + kt) * 64 + lane];
            UBr[kt] = wUr[((8 + it) * 4 + kt) * 64 + lane];
            UBh[kt] = wUr[((16 + it) * 4 + kt) * 64 + lane];
        }
        int c = it * 16 + l15;
        float bz  = br[c] + br[384 + c];
        float brr = br[128 + c] + br[512 + c];
        float bx  = br[256 + c];
        float bh  = br[640 + c];

        f32x4 az  = (f32x4){0.f, 0.f, 0.f, 0.f};
        f32x4 ar_ = (f32x4){0.f, 0.f, 0.f, 0.f};
        f32x4 acx = (f32x4){0.f, 0.f, 0.f, 0.f};
        f32x4 ach = (f32x4){0.f, 0.f, 0.f, 0.f};
        #pragma unroll
        for (int kt = 0; kt < 2; ++kt) {
            az  = __builtin_amdgcn_mfma_f32_16x16x32_f16(AXn[kt], WBz[kt], az, 0, 0, 0);
            ar_ = __builtin_amdgcn_mfma_f32_16x16x32_f16(AXn[kt], WBr[kt], ar_, 0, 0, 0);
            acx = __builtin_amdgcn_mfma_f32_16x16x32_f16(AXn[kt], WBx[kt], acx, 0, 0, 0);
        }
        #pragma unroll
        for (int kt = 0; kt < 4; ++kt) {
            az  = __builtin_amdgcn_mfma_f32_16x16x32_f16(AHro[kt], UBz[kt], az, 0, 0, 0);
            ar_ = __builtin_amdgcn_mfma_f32_16x16x32_f16(AHro[kt], UBr[kt], ar_, 0, 0, 0);
            ach = __builtin_amdgcn_mfma_f32_16x16x32_f16(AHro[kt], UBh[kt], ach, 0, 0, 0);
        }
        #pragma unroll
        for (int r = 0; r < 4; ++r) {
            int e = e0 + hi * 4 + r;
            int ecl = min(e, E - 1);
            float z = fast_sig(az[r] + bz);
            float rr = fast_sig(ar_[r] + brr);
            float cc = fast_tanh(acx[r] + bx + rr * (ach[r] + bh));
            float hp = (float)hro[(size_t)ecl * R + c];
            if (e < E) hro[(size_t)e * R + c] = (_Float16)(z * hp + (1.0f - z) * cc);
        }
    }
}

// ---------------------------------------------------------------------------
// Output: out[g] = b_out + sum_{e: gid[e]==g} dot(hro[e], W_out)
// gids sorted -> wave-level segmented scan; sentinel g=-1 for OOB lanes.
// ---------------------------------------------------------------------------
__global__ void out_init_kernel(float* __restrict__ out, const float* __restrict__ b_out, int G) {
    int g = blockIdx.x * blockDim.x + threadIdx.x;
    if (g < G) out[g] = b_out[0];
}

__global__ __launch_bounds__(256) void out_kernel(
    const _Float16* __restrict__ hro,
    const int* __restrict__ gid,
    const float* __restrict__ Wout,
    float* __restrict__ out,
    int E)
{
    int e = blockIdx.x * 256 + threadIdx.x;
    int lane = threadIdx.x & 63;
    int ec = min(e, E - 1);
    const half8* hp = reinterpret_cast<const half8*>(hro + (size_t)ec * R);
    float s = 0.0f;
    #pragma unroll
    for (int kk = 0; kk < R / 8; ++kk) {
        half8 v = hp[kk];
        #pragma unroll
        for (int j = 0; j < 8; ++j)
            s = fmaf((float)v[j], Wout[kk * 8 + j], s);
    }
    bool valid = (e < E);
    if (!valid) s = 0.0f;
    int g = valid ? gid[ec] : -1;
    #pragma unroll
    for (int d = 1; d < 64; d <<= 1) {
        float t = __shfl_up(s, d);
        int kg = __shfl_up(g, d);
        if (lane >= d && kg == g) s += t;
    }
    int gnext = __shfl_down(g, 1);
    bool tail = (lane == 63) || (gnext != g);
    if (tail && valid) unsafeAtomicAdd(out + g, s);
}

// ---------------------------------------------------------------------------
extern "C" void kernel_launch(void* const* d_in, const int* in_sizes, int n_in,
                              void* d_out, int out_size, void* d_ws, size_t ws_size,
                              hipStream_t stream) {
    const float* link_state = (const float*)d_in[0];
    const int*   first      = (const int*)d_in[1];
    const int*   second     = (const int*)d_in[2];
    const int*   gids       = (const int*)d_in[3];
    const float* Wm         = (const float*)d_in[5];
    const float* bm         = (const float*)d_in[6];
    const float* Wu         = (const float*)d_in[7];
    const float* Uu         = (const float*)d_in[8];
    const float* bu         = (const float*)d_in[9];
    const float* Wr         = (const float*)d_in[10];
    const float* Ur         = (const float*)d_in[11];
    const float* brb        = (const float*)d_in[12];
    const float* Wout       = (const float*)d_in[13];
    const float* bout       = (const float*)d_in[14];

    const int E = in_sizes[0] / D;
    const int M = in_sizes[1];
    const int G = out_size;

    char* p = (char*)d_ws;
    auto carve = [&](size_t bytes) {
        void* r = (void*)p;
        p += (bytes + 255) & ~(size_t)255;
        return r;
    };
    _Float16*  hA   = (_Float16*)carve((size_t)E * D * 2);
    _Float16*  hB   = (_Float16*)carve((size_t)E * D * 2);
    _Float16*  hro  = (_Float16*)carve((size_t)E * R * 2);
    int*       perm = (int*)carve((size_t)M * 4);
    int2*      fs   = (int2*)carve((size_t)M * 8);
    int*       cnt  = (int*)carve((size_t)E * 4);
    int*       cur  = (int*)carve((size_t)E * 4);
    int*       off  = (int*)carve((size_t)(E + 1) * 4);
    int*       bsum = (int*)carve(4096 * 4);
    _Float16*  wWm  = (_Float16*)carve(8192 * 2);
    _Float16*  wWu  = (_Float16*)carve(12288 * 2);
    _Float16*  wUu  = (_Float16*)carve(12288 * 2);
    _Float16*  wWr  = (_Float16*)carve(24576 * 2);
    _Float16*  wUr  = (_Float16*)carve(49152 * 2);

    hipMemsetAsync(hro, 0, (size_t)E * R * 2, stream);
    hipMemsetAsync(cnt, 0, (size_t)E * 4, stream);
    hipMemsetAsync(cur, 0, (size_t)E * 4, stream);

    h16_init<<<(E * D + 255) / 256, 256, 0, stream>>>(link_state, hA, E * D);
    swizzle_all<<<dim3(192, 5), 256, 0, stream>>>(Wm, Wu, Uu, Wr, Ur,
                                                  wWm, wWu, wUu, wWr, wUr);

    const int NB = (E + 255) / 256;   // 391 for E=100k; scan_part handles <=1024
    hist_kernel<<<(M + 255) / 256, 256, 0, stream>>>(second, cnt, M);
    scan_bsum<<<NB, 256, 0, stream>>>(cnt, bsum, E);
    scan_part<<<1, 1024, 0, stream>>>(bsum, NB);
    scan_final<<<NB, 256, 0, stream>>>(cnt, bsum, off, E);
    scatter_kernel<<<(M + 255) / 256, 256, 0, stream>>>(second, off, cur, perm, M);
    fs_pack<<<(M + 255) / 256, 256, 0, stream>>>(first, second, perm, fs, M);

    const int e_blocks = (E + 63) / 64;   // 4 waves x 16 edges per block

    _Float16* hin = hA;
    _Float16* hout = hB;
    for (int t = 0; t < NSTEPS; ++t) {
        step_fused<<<e_blocks, 256, 0, stream>>>(hin, hout, hro, fs, off,
                                                 (const half8*)wWm, bm,
                                                 (const half8*)wWu, (const half8*)wUu, bu,
                                                 (const half8*)wWr, (const half8*)wUr, brb,
                                                 E, M);
        _Float16* tmp = hin; hin = hout; hout = tmp;
    }

    out_init_kernel<<<(G + 255) / 256, 256, 0, stream>>>((float*)d_out, bout, G);
    out_kernel<<<(E + 255) / 256, 256, 0, stream>>>(hro, gids, Wout, (float*)d_out, E);
}